// Round 2
// baseline (1003.711 us; speedup 1.0000x reference)
//
#include <hip/hip_runtime.h>

// GCN forward, bucket-resident aggregation (R15): CSR build DELETED.
//   binA2: per-block LDS radix partition -> 512 dst-range buckets; edges land
//     in staging as (loc<<20)|src, bucket-contiguous. Register-staged loads
//     (dst read once), CHUNK=4096 -> 3 blocks/CU.
//   countB: per-bucket LDS hist -> dinv only (needed by gemm1 pre-scale).
//   gemm1: xwd = (x@W1)*dinv, bf16 64B rows, 4 thr/node x 4 nodes/thr.
//   aggB1: one block per bucket; node accumulators fp32 in LDS (stride 33);
//     4 lanes/edge gather xwd[src] (request-rate bound ~53us floor, R13) +
//     8 ds_add_f32 each; epilogue fuses gemm2 (relu+32x16 matvec) -> h2wd.
//   aggB2: same with 16-wide rows (stride 17), 2 lanes/edge; epilogue fuses
//     the head (relu dot Wf + bf) -> out.
// R4/R9 lesson (atomic agg loses 5-10x) applies to GLOBAL atomics; LDS
//   ds_add_f32 within a bucket block is ~400K ops/CU, well under the gather
//   floor and on a different pipe than VMEM.
// R13 lesson: gather is request-rate bound; single pass per layer.

#define NBUCK 512
#define BCAP 8192    // bucket capacity; mean ~6272, sd ~79 -> 24 sigma margin
#define CHUNK 4096   // edges per binA2 block -> 782 blocks (~3/CU)
#define NPBMAX 256   // max nodes per bucket supported by LDS sizing

__device__ __forceinline__ unsigned f2bf(float f) {  // RNE fp32->bf16
    unsigned u = __float_as_uint(f);
    return (u + 0x7FFFu + ((u >> 16) & 1u)) >> 16;
}
__device__ __forceinline__ float bflo(unsigned u) { return __uint_as_float(u << 16); }
__device__ __forceinline__ float bfhi(unsigned u) { return __uint_as_float(u & 0xFFFF0000u); }

// Phase A: block-local radix partition, bulk append to global staging.
// 512 threads x 8 edges each, fully unrolled register staging (no scratch).
__global__ __launch_bounds__(512) void binA2_kernel(
        const int* __restrict__ src, const int* __restrict__ dst,
        int* __restrict__ bcur, unsigned* __restrict__ staging, int E, int NPB) {
    __shared__ unsigned packed[CHUNK];         // 16 KB
    __shared__ unsigned short buckb[CHUNK];    // 8 KB
    __shared__ int hist[NBUCK];                // 2 KB each
    __shared__ int scan_[NBUCK];
    __shared__ int lstart[NBUCK];
    __shared__ int lcur[NBUCK];
    __shared__ int gbase[NBUCK];
    int tid = threadIdx.x;
    int start = blockIdx.x * CHUNK;
    int sz = min(CHUNK, E - start);

    unsigned dreg[8], sreg[8];
    hist[tid] = 0;
#pragma unroll
    for (int c = 0; c < 8; ++c) {           // compile-time indices -> VGPRs
        int i = tid + c * 512;
        if (i < sz) {
            dreg[c] = (unsigned)dst[start + i];
            sreg[c] = (unsigned)src[start + i];
        } else {
            dreg[c] = 0xFFFFFFFFu;          // sentinel: skip
        }
    }
    __syncthreads();
#pragma unroll
    for (int c = 0; c < 8; ++c)
        if (dreg[c] != 0xFFFFFFFFu) atomicAdd(&hist[dreg[c] / (unsigned)NPB], 1);
    __syncthreads();
    int v = hist[tid];
    scan_[tid] = v;
    __syncthreads();
    for (int dd = 1; dd < NBUCK; dd <<= 1) {
        int t = (tid >= dd) ? scan_[tid - dd] : 0;
        __syncthreads();
        scan_[tid] += t;
        __syncthreads();
    }
    lstart[tid] = scan_[tid] - v;
    lcur[tid] = 0;
    gbase[tid] = atomicAdd(&bcur[tid], v);  // one reservation per (block,bucket)
    __syncthreads();
#pragma unroll
    for (int c = 0; c < 8; ++c) {
        if (dreg[c] == 0xFFFFFFFFu) continue;
        unsigned d = dreg[c];
        unsigned b = d / (unsigned)NPB;
        unsigned loc = d - b * (unsigned)NPB;
        int pos = atomicAdd(&lcur[b], 1);
        int si = lstart[b] + pos;
        packed[si] = (loc << 20) | sreg[c];  // loc<256 (12b avail), src<2^20
        buckb[si] = (unsigned short)b;
    }
    __syncthreads();
    for (int i = tid; i < sz; i += 512) {
        unsigned b = buckb[i];
        int dsti = gbase[b] + (i - lstart[b]);
        if (dsti < BCAP)
            staging[(size_t)b * BCAP + dsti] = packed[i];
    }
}

// Per-bucket degree histogram -> dinv (needed by gemm1's pre-scale).
__global__ __launch_bounds__(512) void countB_kernel(
        const int* __restrict__ bcur, const unsigned* __restrict__ staging,
        float* __restrict__ dinv, int N, int NPB) {
    __shared__ int hist[NPBMAX];
    int b = blockIdx.x;
    int tid = threadIdx.x;
    if (tid < NPBMAX) hist[tid] = 0;
    __syncthreads();
    int sz = min(bcur[b], BCAP);
    const unsigned* se = staging + (size_t)b * BCAP;
    for (int i = tid; i < sz; i += 512)
        atomicAdd(&hist[se[i] >> 20], 1);
    __syncthreads();
    int n0 = b * NPB;
    if (tid < NPB && n0 + tid < N)
        dinv[n0 + tid] = rsqrtf((float)(hist[tid] + 1));  // +1 self-loop
}

// xwd(bf16) = (x @ W1) * dinv[node].  4 threads/node x 8 cols x 4 nodes/thread.
__global__ __launch_bounds__(256) void gemm1_kernel(
        const float* __restrict__ x, const float* __restrict__ W1,
        const float* __restrict__ dinv, unsigned* __restrict__ xwd, int N) {
    __shared__ float ws_[128 * 32];
    for (int i = threadIdx.x; i < 128 * 32; i += 256) ws_[i] = W1[i];
    __syncthreads();
    int t = threadIdx.x;
    int jq = (t & 3) * 8;  // 8 output cols
    int n0 = blockIdx.x * 256 + (t >> 2) * 4;
    if (n0 >= N) return;
    int nc0 = min(n0 + 0, N - 1);
    int nc1 = min(n0 + 1, N - 1);
    int nc2 = min(n0 + 2, N - 1);
    int nc3 = min(n0 + 3, N - 1);
    const float4* xr0 = (const float4*)(x + (size_t)nc0 * 128);
    const float4* xr1 = (const float4*)(x + (size_t)nc1 * 128);
    const float4* xr2 = (const float4*)(x + (size_t)nc2 * 128);
    const float4* xr3 = (const float4*)(x + (size_t)nc3 * 128);
    float acc[4][8];
#pragma unroll
    for (int n = 0; n < 4; ++n)
#pragma unroll
        for (int j = 0; j < 8; ++j) acc[n][j] = 0.0f;
#pragma unroll 2
    for (int k4 = 0; k4 < 32; ++k4) {
        const float* wb = ws_ + (k4 * 4) * 32 + jq;
        float4 a0 = *(const float4*)(wb);
        float4 a1 = *(const float4*)(wb + 4);
        float4 b0 = *(const float4*)(wb + 32);
        float4 b1v = *(const float4*)(wb + 36);
        float4 c0 = *(const float4*)(wb + 64);
        float4 c1 = *(const float4*)(wb + 68);
        float4 d0 = *(const float4*)(wb + 96);
        float4 d1 = *(const float4*)(wb + 100);
        float4 xv0 = xr0[k4];
        float4 xv1 = xr1[k4];
        float4 xv2 = xr2[k4];
        float4 xv3 = xr3[k4];
#pragma unroll
        for (int n = 0; n < 4; ++n) {
            float4 xv = (n == 0) ? xv0 : (n == 1) ? xv1 : (n == 2) ? xv2 : xv3;
            acc[n][0] += xv.x * a0.x + xv.y * b0.x + xv.z * c0.x + xv.w * d0.x;
            acc[n][1] += xv.x * a0.y + xv.y * b0.y + xv.z * c0.y + xv.w * d0.y;
            acc[n][2] += xv.x * a0.z + xv.y * b0.z + xv.z * c0.z + xv.w * d0.z;
            acc[n][3] += xv.x * a0.w + xv.y * b0.w + xv.z * c0.w + xv.w * d0.w;
            acc[n][4] += xv.x * a1.x + xv.y * b1v.x + xv.z * c1.x + xv.w * d1.x;
            acc[n][5] += xv.x * a1.y + xv.y * b1v.y + xv.z * c1.y + xv.w * d1.y;
            acc[n][6] += xv.x * a1.z + xv.y * b1v.z + xv.z * c1.z + xv.w * d1.z;
            acc[n][7] += xv.x * a1.w + xv.y * b1v.w + xv.z * c1.w + xv.w * d1.w;
        }
    }
#pragma unroll
    for (int n = 0; n < 4; ++n) {
        int node = n0 + n;
        if (node >= N) break;
        float d = dinv[node];
        unsigned pk0 = f2bf(acc[n][0] * d) | (f2bf(acc[n][1] * d) << 16);
        unsigned pk1 = f2bf(acc[n][2] * d) | (f2bf(acc[n][3] * d) << 16);
        unsigned pk2 = f2bf(acc[n][4] * d) | (f2bf(acc[n][5] * d) << 16);
        unsigned pk3 = f2bf(acc[n][6] * d) | (f2bf(acc[n][7] * d) << 16);
        ((uint4*)(xwd + (size_t)node * 16))[t & 3] = make_uint4(pk0, pk1, pk2, pk3);
    }
}

// Layer-1 aggregate over staged (unsorted-within-bucket) edges with LDS fp32
// accumulators + fused gemm2 epilogue -> h2wd bf16.  One block per bucket.
__global__ __launch_bounds__(512) void aggB1_kernel(
        const int* __restrict__ bcur, const unsigned* __restrict__ staging,
        const float* __restrict__ dinv, const unsigned* __restrict__ xwd,
        const float* __restrict__ b1, const float* __restrict__ W2,
        unsigned* __restrict__ h2wd, int N, int NPB) {
    __shared__ float acc[NPBMAX * 33];   // stride 33: bank = (loc+col)%32
    __shared__ float ws2[32 * 16];
    __shared__ float bs1[32];
    int b = blockIdx.x;
    int tid = threadIdx.x;
    int n0 = b * NPB;
    int nn = min(NPB, N - n0);
    if (nn <= 0) return;
    if (tid < 512) ws2[tid] = W2[tid];
    if (tid < 32) bs1[tid] = b1[tid];
    // self-term init: 4 threads per node unpack its xwd row
    for (int i = tid; i < nn * 4; i += 512) {
        int loc = i >> 2, q = i & 3;
        uint4 v = ((const uint4*)(xwd + (size_t)(n0 + loc) * 16))[q];
        float* a = acc + loc * 33 + q * 8;
        a[0] = bflo(v.x); a[1] = bfhi(v.x);
        a[2] = bflo(v.y); a[3] = bfhi(v.y);
        a[4] = bflo(v.z); a[5] = bfhi(v.z);
        a[6] = bflo(v.w); a[7] = bfhi(v.w);
    }
    __syncthreads();
    int sz = min(bcur[b], BCAP);
    const unsigned* se = staging + (size_t)b * BCAP;
    int q = tid & 3;                         // 16B slice of the 64B row
    for (int e = tid >> 2; e < sz; e += 128) {
        unsigned p = se[e];                  // 4 lanes same addr -> 1 request
        int loc = p >> 20;
        int s = (int)(p & 0xFFFFFu);
        uint4 v = ((const uint4*)(xwd + (size_t)s * 16))[q];
        float* a = acc + loc * 33 + q * 8;
        atomicAdd(&a[0], bflo(v.x)); atomicAdd(&a[1], bfhi(v.x));
        atomicAdd(&a[2], bflo(v.y)); atomicAdd(&a[3], bfhi(v.y));
        atomicAdd(&a[4], bflo(v.z)); atomicAdd(&a[5], bfhi(v.z));
        atomicAdd(&a[6], bflo(v.w)); atomicAdd(&a[7], bfhi(v.w));
    }
    __syncthreads();
    // fused gemm2 epilogue: h2wd = (relu(acc*dv + b1) @ W2) * dv
    for (int loc = tid; loc < nn; loc += 512) {
        int node = n0 + loc;
        float dv = dinv[node];
        const float* a = acc + loc * 33;     // bank (loc+k)%32: conflict-free
        float h[32];
#pragma unroll
        for (int k = 0; k < 32; ++k) h[k] = fmaxf(a[k] * dv + bs1[k], 0.0f);
        float o[16];
#pragma unroll
        for (int j = 0; j < 16; ++j) o[j] = 0.0f;
#pragma unroll
        for (int k = 0; k < 32; ++k) {
            float hv = h[k];
#pragma unroll
            for (int j = 0; j < 16; ++j) o[j] += hv * ws2[k * 16 + j];
        }
        unsigned pk[8];
#pragma unroll
        for (int j = 0; j < 8; ++j)
            pk[j] = f2bf(o[2 * j] * dv) | (f2bf(o[2 * j + 1] * dv) << 16);
        uint4* hp = (uint4*)(h2wd + (size_t)node * 8);
        hp[0] = make_uint4(pk[0], pk[1], pk[2], pk[3]);
        hp[1] = make_uint4(pk[4], pk[5], pk[6], pk[7]);
    }
}

// Layer-2 aggregate over staged edges + fused head -> out.  2 lanes/edge.
__global__ __launch_bounds__(512) void aggB2_kernel(
        const int* __restrict__ bcur, const unsigned* __restrict__ staging,
        const float* __restrict__ dinv, const unsigned* __restrict__ h2wd,
        const float* __restrict__ b2, const float* __restrict__ Wf,
        const float* __restrict__ bfp, float* __restrict__ out, int N, int NPB) {
    __shared__ float acc[NPBMAX * 17];   // stride 17 (odd): 2-way max on reads
    __shared__ float bs2[16];
    __shared__ float wf[16];
    int b = blockIdx.x;
    int tid = threadIdx.x;
    int n0 = b * NPB;
    int nn = min(NPB, N - n0);
    if (nn <= 0) return;
    if (tid < 16) { bs2[tid] = b2[tid]; wf[tid] = Wf[tid]; }
    for (int i = tid; i < nn * 2; i += 512) {
        int loc = i >> 1, q = i & 1;
        uint4 v = ((const uint4*)(h2wd + (size_t)(n0 + loc) * 8))[q];
        float* a = acc + loc * 17 + q * 8;
        a[0] = bflo(v.x); a[1] = bfhi(v.x);
        a[2] = bflo(v.y); a[3] = bfhi(v.y);
        a[4] = bflo(v.z); a[5] = bfhi(v.z);
        a[6] = bflo(v.w); a[7] = bfhi(v.w);
    }
    __syncthreads();
    int sz = min(bcur[b], BCAP);
    const unsigned* se = staging + (size_t)b * BCAP;
    int q = tid & 1;
    for (int e = tid >> 1; e < sz; e += 256) {
        unsigned p = se[e];
        int loc = p >> 20;
        int s = (int)(p & 0xFFFFFu);
        uint4 v = ((const uint4*)(h2wd + (size_t)s * 8))[q];
        float* a = acc + loc * 17 + q * 8;
        atomicAdd(&a[0], bflo(v.x)); atomicAdd(&a[1], bfhi(v.x));
        atomicAdd(&a[2], bflo(v.y)); atomicAdd(&a[3], bfhi(v.y));
        atomicAdd(&a[4], bflo(v.z)); atomicAdd(&a[5], bfhi(v.z));
        atomicAdd(&a[6], bflo(v.w)); atomicAdd(&a[7], bfhi(v.w));
    }
    __syncthreads();
    // fused head: out = relu(acc*dv + b2) . Wf + bf
    for (int loc = tid; loc < nn; loc += 512) {
        int node = n0 + loc;
        float dv = dinv[node];
        const float* a = acc + loc * 17;
        float part = 0.0f;
#pragma unroll
        for (int k = 0; k < 16; ++k)
            part += fmaxf(a[k] * dv + bs2[k], 0.0f) * wf[k];
        out[node] = part + bfp[0];
    }
}

extern "C" void kernel_launch(void* const* d_in, const int* in_sizes, int n_in,
                              void* d_out, int out_size, void* d_ws, size_t ws_size,
                              hipStream_t stream) {
    const float* x  = (const float*)d_in[0];
    const int*   ei = (const int*)d_in[1];
    const float* W1 = (const float*)d_in[2];
    const float* b1 = (const float*)d_in[3];
    const float* W2 = (const float*)d_in[4];
    const float* b2 = (const float*)d_in[5];
    const float* Wf = (const float*)d_in[6];
    const float* bf = (const float*)d_in[7];

    int N = in_sizes[0] / 128;
    int E = in_sizes[1] / 2;
    const int* src = ei;       // edge_index[0]
    const int* dst = ei + E;   // edge_index[1]
    int NPB = (N + NBUCK - 1) / NBUCK;  // 196 for N=100k (must be <= NPBMAX)

    // Workspace layout (~27 MB total; no counts/offs/csr anymore)
    size_t Np = ((size_t)N + 3) & ~(size_t)3;
    int* bcur        = (int*)d_ws;                  // NBUCK
    float* dinv      = (float*)(bcur + NBUCK);      // Np
    unsigned* xwd    = (unsigned*)(dinv + Np);      // 16*Np u32 (bf16, 64B rows)
    unsigned* h2wd   = xwd + 16 * Np;               // 8*Np u32 (bf16, 32B rows)
    unsigned* staging= h2wd + 8 * Np;               // NBUCK*BCAP u32 = 16.8 MB
    float* out       = (float*)d_out;

    int nbC  = (E + CHUNK - 1) / CHUNK;
    int nbG1 = (N + 255) / 256;

    hipMemsetAsync(bcur, 0, NBUCK * sizeof(int), stream);
    binA2_kernel<<<nbC, 512, 0, stream>>>(src, dst, bcur, staging, E, NPB);
    countB_kernel<<<NBUCK, 512, 0, stream>>>(bcur, staging, dinv, N, NPB);
    gemm1_kernel<<<nbG1, 256, 0, stream>>>(x, W1, dinv, xwd, N);
    aggB1_kernel<<<NBUCK, 512, 0, stream>>>(bcur, staging, dinv, xwd,
                                            b1, W2, h2wd, N, NPB);
    aggB2_kernel<<<NBUCK, 512, 0, stream>>>(bcur, staging, dinv, h2wd,
                                            b2, Wf, bf, out, N, NPB);
}

// Round 3
// 616.807 us; speedup vs baseline: 1.6273x; 1.6273x over previous
//
#include <hip/hip_runtime.h>

// GCN forward via direct atomic CSR build + register-gather aggregation.
// R15 lesson (NEW): per-edge atomic *float accumulation* loses badly even in
//   LDS (591us vs 53us gather floor: occupancy collapse + serialized dependent
//   chain + spill). Gather-with-register-accum is the only fast float path.
// R16: CSR build itself switched from two-phase LDS radix staging (binA2+
//   buildB, ~100us, 16.8MB staging round-trip) to direct INT atomics:
//   countA (hist) -> scan1/2/3 (hierarchical prefix + dinv + cursor) ->
//   scatter (slot = atomicAdd(cursor)). Int atomics on L2-resident arrays
//   are request-rate cheap (~6.4M requests total).
//   gemm1: xwd = (x@W1)*dinv, bf16 64B rows, 4 thr/node x 4 nodes/thr.
//   aggF: layer-1 gather (4 lanes/node, request-rate bound ~53us floor, R13)
//     fused with gemm2 (per-lane 8x16 matvec + 12-shuffle butterfly) -> h2wd.
//   aggS16f: 2 lanes/node gather + fused head (8 FMA + 1 shfl_xor) -> out.
// R7: no wave-serial epilogues in gather kernels.
// R13: gather is request-rate bound; single pass per layer is optimal.

#define TPB 256

__device__ __forceinline__ unsigned f2bf(float f) {  // RNE fp32->bf16
    unsigned u = __float_as_uint(f);
    return (u + 0x7FFFu + ((u >> 16) & 1u)) >> 16;
}
__device__ __forceinline__ float bflo(unsigned u) { return __uint_as_float(u << 16); }
__device__ __forceinline__ float bfhi(unsigned u) { return __uint_as_float(u & 0xFFFF0000u); }

// Degree histogram: 3.2M int atomics over 100K counters (L2-resident).
__global__ __launch_bounds__(256) void countA_kernel(
        const int* __restrict__ dst, int* __restrict__ counts, int E) {
    int stride = gridDim.x * 256;
    for (int i = blockIdx.x * 256 + threadIdx.x; i < E; i += stride)
        atomicAdd(&counts[dst[i]], 1);
}

// Block-level exclusive scan of counts (512/block) + dinv. offs gets the
// block-local exclusive prefix; bsum gets the block total.
__global__ __launch_bounds__(512) void scan1_kernel(
        const int* __restrict__ counts, int* __restrict__ offs,
        int* __restrict__ bsum, float* __restrict__ dinv, int N) {
    __shared__ int s[512];
    int tid = threadIdx.x;
    int g = blockIdx.x * 512 + tid;
    int c = (g < N) ? counts[g] : 0;
    s[tid] = c;
    __syncthreads();
    for (int d = 1; d < 512; d <<= 1) {
        int t = (tid >= d) ? s[tid - d] : 0;
        __syncthreads();
        s[tid] += t;
        __syncthreads();
    }
    if (g < N) {
        offs[g] = s[tid] - c;                 // block-local exclusive
        dinv[g] = rsqrtf((float)(c + 1));     // +1 self-loop
    }
    if (tid == 511) bsum[blockIdx.x] = s[511];
}

// Scan the block sums (nb <= 512) in-place -> exclusive prefixes.
__global__ __launch_bounds__(512) void scan2_kernel(int* __restrict__ bsum, int nb) {
    __shared__ int s[512];
    int tid = threadIdx.x;
    int v = (tid < nb) ? bsum[tid] : 0;
    s[tid] = v;
    __syncthreads();
    for (int d = 1; d < 512; d <<= 1) {
        int t = (tid >= d) ? s[tid - d] : 0;
        __syncthreads();
        s[tid] += t;
        __syncthreads();
    }
    if (tid < nb) bsum[tid] = s[tid] - v;     // exclusive
}

// Finalize offs (+ block prefix) and init the scatter cursor.
__global__ __launch_bounds__(256) void scan3_kernel(
        int* __restrict__ offs, const int* __restrict__ bsum,
        int* __restrict__ cursor, int N) {
    int g = blockIdx.x * 256 + threadIdx.x;
    if (g < N) {
        int o = offs[g] + bsum[g >> 9];
        offs[g] = o;
        cursor[g] = o;
    }
}

// CSR placement: slot via int atomic on the absolute cursor.
__global__ __launch_bounds__(256) void scatter_kernel(
        const int* __restrict__ src, const int* __restrict__ dst,
        int* __restrict__ cursor, int* __restrict__ csr_src, int E) {
    int stride = gridDim.x * 256;
    for (int i = blockIdx.x * 256 + threadIdx.x; i < E; i += stride) {
        int d = dst[i];
        int pos = atomicAdd(&cursor[d], 1);
        csr_src[pos] = src[i];
    }
}

// xwd(bf16) = (x @ W1) * dinv[node].  4 threads/node x 8 cols x 4 nodes/thread.
__global__ __launch_bounds__(256) void gemm1_kernel(
        const float* __restrict__ x, const float* __restrict__ W1,
        const float* __restrict__ dinv, unsigned* __restrict__ xwd, int N) {
    __shared__ float ws_[128 * 32];
    for (int i = threadIdx.x; i < 128 * 32; i += 256) ws_[i] = W1[i];
    __syncthreads();
    int t = threadIdx.x;
    int jq = (t & 3) * 8;  // 8 output cols
    int n0 = blockIdx.x * 256 + (t >> 2) * 4;
    if (n0 >= N) return;
    int nc0 = min(n0 + 0, N - 1);
    int nc1 = min(n0 + 1, N - 1);
    int nc2 = min(n0 + 2, N - 1);
    int nc3 = min(n0 + 3, N - 1);
    const float4* xr0 = (const float4*)(x + (size_t)nc0 * 128);
    const float4* xr1 = (const float4*)(x + (size_t)nc1 * 128);
    const float4* xr2 = (const float4*)(x + (size_t)nc2 * 128);
    const float4* xr3 = (const float4*)(x + (size_t)nc3 * 128);
    float acc[4][8];
#pragma unroll
    for (int n = 0; n < 4; ++n)
#pragma unroll
        for (int j = 0; j < 8; ++j) acc[n][j] = 0.0f;
#pragma unroll 2
    for (int k4 = 0; k4 < 32; ++k4) {
        const float* wb = ws_ + (k4 * 4) * 32 + jq;
        float4 a0 = *(const float4*)(wb);
        float4 a1 = *(const float4*)(wb + 4);
        float4 b0 = *(const float4*)(wb + 32);
        float4 b1v = *(const float4*)(wb + 36);
        float4 c0 = *(const float4*)(wb + 64);
        float4 c1 = *(const float4*)(wb + 68);
        float4 d0 = *(const float4*)(wb + 96);
        float4 d1 = *(const float4*)(wb + 100);
        float4 xv0 = xr0[k4];
        float4 xv1 = xr1[k4];
        float4 xv2 = xr2[k4];
        float4 xv3 = xr3[k4];
#pragma unroll
        for (int n = 0; n < 4; ++n) {
            float4 xv = (n == 0) ? xv0 : (n == 1) ? xv1 : (n == 2) ? xv2 : xv3;
            acc[n][0] += xv.x * a0.x + xv.y * b0.x + xv.z * c0.x + xv.w * d0.x;
            acc[n][1] += xv.x * a0.y + xv.y * b0.y + xv.z * c0.y + xv.w * d0.y;
            acc[n][2] += xv.x * a0.z + xv.y * b0.z + xv.z * c0.z + xv.w * d0.z;
            acc[n][3] += xv.x * a0.w + xv.y * b0.w + xv.z * c0.w + xv.w * d0.w;
            acc[n][4] += xv.x * a1.x + xv.y * b1v.x + xv.z * c1.x + xv.w * d1.x;
            acc[n][5] += xv.x * a1.y + xv.y * b1v.y + xv.z * c1.y + xv.w * d1.y;
            acc[n][6] += xv.x * a1.z + xv.y * b1v.z + xv.z * c1.z + xv.w * d1.z;
            acc[n][7] += xv.x * a1.w + xv.y * b1v.w + xv.z * c1.w + xv.w * d1.w;
        }
    }
#pragma unroll
    for (int n = 0; n < 4; ++n) {
        int node = n0 + n;
        if (node >= N) break;
        float d = dinv[node];
        unsigned pk0 = f2bf(acc[n][0] * d) | (f2bf(acc[n][1] * d) << 16);
        unsigned pk1 = f2bf(acc[n][2] * d) | (f2bf(acc[n][3] * d) << 16);
        unsigned pk2 = f2bf(acc[n][4] * d) | (f2bf(acc[n][5] * d) << 16);
        unsigned pk3 = f2bf(acc[n][6] * d) | (f2bf(acc[n][7] * d) << 16);
        ((uint4*)(xwd + (size_t)node * 16))[t & 3] = make_uint4(pk0, pk1, pk2, pk3);
    }
}

// Layer-1 aggregate FUSED with gemm2: 4 lanes/node gather, register accum,
// then h2wd = (relu(agg*dv + b1) @ W2) * dv via LDS W2 + 12-shuffle butterfly.
__global__ __launch_bounds__(256) void aggF_kernel(
        const int* __restrict__ offs, const int* __restrict__ counts,
        const int* __restrict__ csr_src, const float* __restrict__ dinv,
        const unsigned* __restrict__ xwd, const float* __restrict__ b1,
        const float* __restrict__ W2, unsigned* __restrict__ h2wd, int N) {
    __shared__ float ws2[32 * 16];
    for (int i = threadIdx.x; i < 512; i += 256) ws2[i] = W2[i];
    __syncthreads();
    int t = threadIdx.x;
    int q = t & 3;                       // 16B slice
    int node = blockIdx.x * 64 + (t >> 2);
    if (node >= N) return;
    int off = offs[node];
    int deg = counts[node];
    float acc[8];
    {
        uint4 v = ((const uint4*)(xwd + (size_t)node * 16))[q];  // self term
        acc[0] = bflo(v.x); acc[1] = bfhi(v.x);
        acc[2] = bflo(v.y); acc[3] = bfhi(v.y);
        acc[4] = bflo(v.z); acc[5] = bfhi(v.z);
        acc[6] = bflo(v.w); acc[7] = bfhi(v.w);
    }
    int i = 0;
    for (; i + 1 < deg; i += 2) {
        int s0 = csr_src[off + i];
        int s1 = csr_src[off + i + 1];
        uint4 v0 = ((const uint4*)(xwd + (size_t)s0 * 16))[q];
        uint4 v1 = ((const uint4*)(xwd + (size_t)s1 * 16))[q];
        acc[0] += bflo(v0.x) + bflo(v1.x); acc[1] += bfhi(v0.x) + bfhi(v1.x);
        acc[2] += bflo(v0.y) + bflo(v1.y); acc[3] += bfhi(v0.y) + bfhi(v1.y);
        acc[4] += bflo(v0.z) + bflo(v1.z); acc[5] += bfhi(v0.z) + bfhi(v1.z);
        acc[6] += bflo(v0.w) + bflo(v1.w); acc[7] += bfhi(v0.w) + bfhi(v1.w);
    }
    if (i < deg) {
        int s = csr_src[off + i];
        uint4 v = ((const uint4*)(xwd + (size_t)s * 16))[q];
        acc[0] += bflo(v.x); acc[1] += bfhi(v.x);
        acc[2] += bflo(v.y); acc[3] += bfhi(v.y);
        acc[4] += bflo(v.z); acc[5] += bfhi(v.z);
        acc[6] += bflo(v.w); acc[7] += bfhi(v.w);
    }
    float dv = dinv[node];
    // fused gemm2: lane q owns k = q*8..q*8+7 of the 32-dim hidden vector
    float part[16];
#pragma unroll
    for (int j = 0; j < 16; ++j) part[j] = 0.0f;
    const float* bq = b1 + q * 8;
#pragma unroll
    for (int k = 0; k < 8; ++k) {
        float h = fmaxf(acc[k] * dv + bq[k], 0.0f);
        const float* wr = ws2 + (q * 8 + k) * 16;
        float4 w0 = *(const float4*)(wr);
        float4 w1 = *(const float4*)(wr + 4);
        float4 w2 = *(const float4*)(wr + 8);
        float4 w3 = *(const float4*)(wr + 12);
        part[0]  += h * w0.x; part[1]  += h * w0.y; part[2]  += h * w0.z; part[3]  += h * w0.w;
        part[4]  += h * w1.x; part[5]  += h * w1.y; part[6]  += h * w1.z; part[7]  += h * w1.w;
        part[8]  += h * w2.x; part[9]  += h * w2.y; part[10] += h * w2.z; part[11] += h * w2.w;
        part[12] += h * w3.x; part[13] += h * w3.y; part[14] += h * w3.z; part[15] += h * w3.w;
    }
    // half-exchange butterfly over the quad: 8 + 4 shfl total.
    float p8[8];
#pragma unroll
    for (int j = 0; j < 8; ++j) {
        float send = (q & 1) ? part[j] : part[j + 8];
        float keep = (q & 1) ? part[j + 8] : part[j];
        p8[j] = keep + __shfl_xor(send, 1, 64);
    }
    float p4[4];
#pragma unroll
    for (int j = 0; j < 4; ++j) {
        float send = (q & 2) ? p8[j] : p8[j + 4];
        float keep = (q & 2) ? p8[j + 4] : p8[j];
        p4[j] = keep + __shfl_xor(send, 2, 64);
    }
    unsigned pk0 = f2bf(p4[0] * dv) | (f2bf(p4[1] * dv) << 16);
    unsigned pk1 = f2bf(p4[2] * dv) | (f2bf(p4[3] * dv) << 16);
    int slot = ((q & 1) << 1) | ((q >> 1) & 1);   // col base /4: q0->0 q1->2 q2->1 q3->3
    ((uint2*)(h2wd + (size_t)node * 8))[slot] = make_uint2(pk0, pk1);
}

// Layer-2 aggregate + fused head, lane-slice: 2 lanes own node's 32B row;
// serial edges (x2 unroll); epilogue = 8 FMA dot + ONE shfl_xor -> out.
__global__ __launch_bounds__(256) void aggS16f_kernel(
        const int* __restrict__ offs, const int* __restrict__ counts,
        const int* __restrict__ csr_src, const float* __restrict__ dinv,
        const unsigned* __restrict__ h2wd,
        const float* __restrict__ b2, const float* __restrict__ Wf,
        const float* __restrict__ bf, float* __restrict__ out, int N) {
    __shared__ float bs_[16];
    __shared__ float wf_[16];
    __shared__ float bfv;
    int t = threadIdx.x;
    if (t < 16) { bs_[t] = b2[t]; wf_[t] = Wf[t]; }
    if (t == 0) bfv = bf[0];
    __syncthreads();
    int q = t & 1;                        // 16B slice (8 feats)
    int node = blockIdx.x * 128 + (t >> 1);
    if (node >= N) return;
    int off = offs[node];
    int deg = counts[node];
    float acc[8];
    {
        uint4 v = ((const uint4*)(h2wd + (size_t)node * 8))[q];  // self term
        acc[0] = bflo(v.x); acc[1] = bfhi(v.x);
        acc[2] = bflo(v.y); acc[3] = bfhi(v.y);
        acc[4] = bflo(v.z); acc[5] = bfhi(v.z);
        acc[6] = bflo(v.w); acc[7] = bfhi(v.w);
    }
    int i = 0;
    for (; i + 1 < deg; i += 2) {
        int s0 = csr_src[off + i];
        int s1 = csr_src[off + i + 1];
        uint4 v0 = ((const uint4*)(h2wd + (size_t)s0 * 8))[q];
        uint4 v1 = ((const uint4*)(h2wd + (size_t)s1 * 8))[q];
        acc[0] += bflo(v0.x) + bflo(v1.x); acc[1] += bfhi(v0.x) + bfhi(v1.x);
        acc[2] += bflo(v0.y) + bflo(v1.y); acc[3] += bfhi(v0.y) + bfhi(v1.y);
        acc[4] += bflo(v0.z) + bflo(v1.z); acc[5] += bfhi(v0.z) + bfhi(v1.z);
        acc[6] += bflo(v0.w) + bflo(v1.w); acc[7] += bfhi(v0.w) + bfhi(v1.w);
    }
    if (i < deg) {
        int s = csr_src[off + i];
        uint4 v = ((const uint4*)(h2wd + (size_t)s * 8))[q];
        acc[0] += bflo(v.x); acc[1] += bfhi(v.x);
        acc[2] += bflo(v.y); acc[3] += bfhi(v.y);
        acc[4] += bflo(v.z); acc[5] += bfhi(v.z);
        acc[6] += bflo(v.w); acc[7] += bfhi(v.w);
    }
    // fused head: out[node] = relu(acc*dv + b2) . Wf + bf  (pair-split dot)
    float dv = dinv[node];
    const float* bq = bs_ + q * 8;
    const float* wq = wf_ + q * 8;
    float part = 0.f;
#pragma unroll
    for (int k = 0; k < 8; ++k)
        part += fmaxf(acc[k] * dv + bq[k], 0.f) * wq[k];
    part += __shfl_xor(part, 1, 64);  // combine the pair's halves
    if (q == 0) out[node] = part + bfv;
}

extern "C" void kernel_launch(void* const* d_in, const int* in_sizes, int n_in,
                              void* d_out, int out_size, void* d_ws, size_t ws_size,
                              hipStream_t stream) {
    const float* x  = (const float*)d_in[0];
    const int*   ei = (const int*)d_in[1];
    const float* W1 = (const float*)d_in[2];
    const float* b1 = (const float*)d_in[3];
    const float* W2 = (const float*)d_in[4];
    const float* b2 = (const float*)d_in[5];
    const float* Wf = (const float*)d_in[6];
    const float* bf = (const float*)d_in[7];

    int N = in_sizes[0] / 128;
    int E = in_sizes[1] / 2;
    const int* src = ei;       // edge_index[0]
    const int* dst = ei + E;   // edge_index[1]

    // Workspace layout (~25 MB)
    size_t Np = ((size_t)N + 3) & ~(size_t)3;
    size_t Ep = ((size_t)E + 3) & ~(size_t)3;
    int* counts   = (int*)d_ws;          // Np
    int* offs     = counts + Np;         // Np
    int* cursor   = offs + Np;           // Np
    int* bsum     = cursor + Np;         // 512
    int* csr_src  = bsum + 512;          // Ep
    float* dinv   = (float*)(csr_src + Ep);      // Np
    unsigned* xwd = (unsigned*)(dinv + Np);      // 16*Np u32 (bf16, 64B rows)
    unsigned* h2wd= xwd + 16 * Np;               // 8*Np u32 (bf16, 32B rows)
    float* out    = (float*)d_out;

    int nbE  = min((E + 255) / 256, 2048);   // grid-stride edge kernels
    int nbS1 = (N + 511) / 512;              // 196 blocks (<= 512)
    int nbN  = (N + 255) / 256;
    int nbG1 = (N + 255) / 256;
    int nbA32 = (N + 63) / 64;   // 64 nodes/block (4 lanes/node)
    int nbA16 = (N + 127) / 128; // 128 nodes/block (2 lanes/node)

    hipMemsetAsync(counts, 0, Np * sizeof(int), stream);
    countA_kernel<<<nbE, 256, 0, stream>>>(dst, counts, E);
    scan1_kernel<<<nbS1, 512, 0, stream>>>(counts, offs, bsum, dinv, N);
    scan2_kernel<<<1, 512, 0, stream>>>(bsum, nbS1);
    scan3_kernel<<<nbN, 256, 0, stream>>>(offs, bsum, cursor, N);
    scatter_kernel<<<nbE, 256, 0, stream>>>(src, dst, cursor, csr_src, E);
    gemm1_kernel<<<nbG1, 256, 0, stream>>>(x, W1, dinv, xwd, N);
    aggF_kernel<<<nbA32, 256, 0, stream>>>(offs, counts, csr_src, dinv, xwd,
                                           b1, W2, h2wd, N);
    aggS16f_kernel<<<nbA16, 256, 0, stream>>>(offs, counts, csr_src, dinv, h2wd,
                                              b2, Wf, bf, out, N);
}

// Round 4
// 253.338 us; speedup vs baseline: 3.9619x; 2.4347x over previous
//
#include <hip/hip_runtime.h>

// GCN forward via two-level CSR build + gather aggregation.
// Lessons ledger:
//   R4/R9:  atomic float aggregation (global) loses 5-10x to register gather.
//   R15:    ...and LDS float atomics lose too (591us: occupancy collapse +
//           serialized dependent chain + spill). Register accum only.
//   R17:    scattered 4B global writes are forbidden: direct atomic CSR
//           scatter hit 196MB HBM write for a 12.8MB payload (15x partial-line
//           amplification across 8 non-coherent L2s) -> 300us. Two-phase radix
//           staging (binA2+buildB) keeps writes bucket-contiguous.
//   R13:    gather is concurrency/latency bound; two L2-resident half-passes
//           (35us x2) lose to one full pass (53.5us). R18 hypothesis: raise
//           in-flight requests per wave (x4 unroll) instead.
//   R7:     no wave-serial epilogues in gather kernels.
// Pipeline:
//   binA2: per-block LDS radix partition -> 512 dst-range buckets.
//   buildB: per-bucket LDS histogram+scan -> counts/offs/dinv + CSR.
//   gemm1: xwd = (x@W1)*dinv, bf16 64B rows, 4 thr/node x 4 nodes/thr.
//   aggF: layer-1 gather (4 lanes/node, x4 unroll) fused with gemm2
//         (per-lane 8x16 matvec + 12-shuffle butterfly) -> h2wd bf16.
//   aggS16f: layer-2 gather (2 lanes/node, x4 unroll) + fused head -> out.

#define TPB 256
#define NBUCK 512
#define BCAP 8192    // bucket capacity; mean ~6272, sd ~79 -> 24 sigma margin
#define CHUNK 8192   // edges per binA2 block

__device__ __forceinline__ unsigned f2bf(float f) {  // RNE fp32->bf16
    unsigned u = __float_as_uint(f);
    return (u + 0x7FFFu + ((u >> 16) & 1u)) >> 16;
}
__device__ __forceinline__ float bflo(unsigned u) { return __uint_as_float(u << 16); }
__device__ __forceinline__ float bfhi(unsigned u) { return __uint_as_float(u & 0xFFFF0000u); }

// Phase A: block-local radix partition, then bulk append to global staging.
__global__ __launch_bounds__(512) void binA2_kernel(
        const int* __restrict__ src, const int* __restrict__ dst,
        int* __restrict__ bcur, unsigned* __restrict__ staging, int E, int NPB) {
    __shared__ unsigned packed[CHUNK];         // 32 KB
    __shared__ unsigned short buckb[CHUNK];    // 16 KB
    __shared__ int hist[NBUCK];
    __shared__ int scan_[NBUCK];
    __shared__ int lstart[NBUCK];
    __shared__ int lcur[NBUCK];
    __shared__ int gbase[NBUCK];
    int tid = threadIdx.x;
    int start = blockIdx.x * CHUNK;
    int sz = min(CHUNK, E - start);

    hist[tid] = 0;
    __syncthreads();
    for (int i = tid; i < sz; i += 512) {
        unsigned d = (unsigned)dst[start + i];
        atomicAdd(&hist[d / (unsigned)NPB], 1);
    }
    __syncthreads();
    int v = hist[tid];
    scan_[tid] = v;
    __syncthreads();
    for (int dd = 1; dd < NBUCK; dd <<= 1) {
        int t = (tid >= dd) ? scan_[tid - dd] : 0;
        __syncthreads();
        scan_[tid] += t;
        __syncthreads();
    }
    lstart[tid] = scan_[tid] - v;
    lcur[tid] = 0;
    gbase[tid] = atomicAdd(&bcur[tid], v);  // one reservation per (block,bucket)
    __syncthreads();
    for (int i = tid; i < sz; i += 512) {
        unsigned d = (unsigned)dst[start + i];
        unsigned s = (unsigned)src[start + i];
        unsigned b = d / (unsigned)NPB;
        unsigned loc = d - b * (unsigned)NPB;
        int pos = atomicAdd(&lcur[b], 1);
        int si = lstart[b] + pos;
        packed[si] = (loc << 20) | s;
        buckb[si] = (unsigned short)b;
    }
    __syncthreads();
    for (int i = tid; i < sz; i += 512) {
        unsigned b = buckb[i];
        int dsti = gbase[b] + (i - lstart[b]);
        if (dsti < BCAP)
            staging[(size_t)b * BCAP + dsti] = packed[i];
    }
}

// Phase B: one block (512 thr) per bucket; hist+scan -> CSR placement.
__global__ void buildB_kernel(const int* __restrict__ bcur,
                              const unsigned* __restrict__ staging,
                              int* __restrict__ offs, int* __restrict__ counts,
                              float* __restrict__ dinv, int* __restrict__ csr_src,
                              int N, int NPB) {
    __shared__ int sb[NBUCK];
    __shared__ int hist[512];
    __shared__ int scan_[512];
    __shared__ int cur[512];
    int b = blockIdx.x;
    int tid = threadIdx.x;
    // inclusive prefix of clamped bucket sizes over NBUCK entries
    if (tid < NBUCK) sb[tid] = min(bcur[tid], BCAP);
    __syncthreads();
    for (int d = 1; d < NBUCK; d <<= 1) {
        int t = 0;
        if (tid < NBUCK && tid >= d) t = sb[tid - d];
        __syncthreads();
        if (tid < NBUCK) sb[tid] += t;
        __syncthreads();
    }
    int sz = min(bcur[b], BCAP);
    int base = (b == 0) ? 0 : sb[b - 1];
    int n0 = b * NPB;
    int nn = min(NPB, N - n0);
    const unsigned* se = staging + (size_t)b * BCAP;

    hist[tid] = 0;
    __syncthreads();
    for (int i = tid; i < sz; i += 512)
        atomicAdd(&hist[se[i] >> 20], 1);
    __syncthreads();
    int h = hist[tid];
    scan_[tid] = h;
    __syncthreads();
    for (int d = 1; d < 512; d <<= 1) {
        int t = (tid >= d) ? scan_[tid - d] : 0;
        __syncthreads();
        scan_[tid] += t;
        __syncthreads();
    }
    int excl = scan_[tid] - h;
    cur[tid] = excl;
    if (tid < nn) {
        int node = n0 + tid;
        offs[node] = base + excl;
        counts[node] = h;
        dinv[node] = rsqrtf((float)(h + 1));  // +1 self-loop
    }
    __syncthreads();
    for (int i = tid; i < sz; i += 512) {
        unsigned p = se[i];
        int pos = atomicAdd(&cur[p >> 20], 1);
        csr_src[base + pos] = (int)(p & 0xFFFFFu);
    }
}

// xwd(bf16) = (x @ W1) * dinv[node].  4 threads/node x 8 cols x 4 nodes/thread.
__global__ __launch_bounds__(256) void gemm1_kernel(
        const float* __restrict__ x, const float* __restrict__ W1,
        const float* __restrict__ dinv, unsigned* __restrict__ xwd, int N) {
    __shared__ float ws_[128 * 32];
    for (int i = threadIdx.x; i < 128 * 32; i += 256) ws_[i] = W1[i];
    __syncthreads();
    int t = threadIdx.x;
    int jq = (t & 3) * 8;  // 8 output cols
    int n0 = blockIdx.x * 256 + (t >> 2) * 4;
    if (n0 >= N) return;
    int nc0 = min(n0 + 0, N - 1);
    int nc1 = min(n0 + 1, N - 1);
    int nc2 = min(n0 + 2, N - 1);
    int nc3 = min(n0 + 3, N - 1);
    const float4* xr0 = (const float4*)(x + (size_t)nc0 * 128);
    const float4* xr1 = (const float4*)(x + (size_t)nc1 * 128);
    const float4* xr2 = (const float4*)(x + (size_t)nc2 * 128);
    const float4* xr3 = (const float4*)(x + (size_t)nc3 * 128);
    float acc[4][8];
#pragma unroll
    for (int n = 0; n < 4; ++n)
#pragma unroll
        for (int j = 0; j < 8; ++j) acc[n][j] = 0.0f;
#pragma unroll 2
    for (int k4 = 0; k4 < 32; ++k4) {
        const float* wb = ws_ + (k4 * 4) * 32 + jq;
        float4 a0 = *(const float4*)(wb);
        float4 a1 = *(const float4*)(wb + 4);
        float4 b0 = *(const float4*)(wb + 32);
        float4 b1v = *(const float4*)(wb + 36);
        float4 c0 = *(const float4*)(wb + 64);
        float4 c1 = *(const float4*)(wb + 68);
        float4 d0 = *(const float4*)(wb + 96);
        float4 d1 = *(const float4*)(wb + 100);
        float4 xv0 = xr0[k4];
        float4 xv1 = xr1[k4];
        float4 xv2 = xr2[k4];
        float4 xv3 = xr3[k4];
#pragma unroll
        for (int n = 0; n < 4; ++n) {
            float4 xv = (n == 0) ? xv0 : (n == 1) ? xv1 : (n == 2) ? xv2 : xv3;
            acc[n][0] += xv.x * a0.x + xv.y * b0.x + xv.z * c0.x + xv.w * d0.x;
            acc[n][1] += xv.x * a0.y + xv.y * b0.y + xv.z * c0.y + xv.w * d0.y;
            acc[n][2] += xv.x * a0.z + xv.y * b0.z + xv.z * c0.z + xv.w * d0.z;
            acc[n][3] += xv.x * a0.w + xv.y * b0.w + xv.z * c0.w + xv.w * d0.w;
            acc[n][4] += xv.x * a1.x + xv.y * b1v.x + xv.z * c1.x + xv.w * d1.x;
            acc[n][5] += xv.x * a1.y + xv.y * b1v.y + xv.z * c1.y + xv.w * d1.y;
            acc[n][6] += xv.x * a1.z + xv.y * b1v.z + xv.z * c1.z + xv.w * d1.z;
            acc[n][7] += xv.x * a1.w + xv.y * b1v.w + xv.z * c1.w + xv.w * d1.w;
        }
    }
#pragma unroll
    for (int n = 0; n < 4; ++n) {
        int node = n0 + n;
        if (node >= N) break;
        float d = dinv[node];
        unsigned pk0 = f2bf(acc[n][0] * d) | (f2bf(acc[n][1] * d) << 16);
        unsigned pk1 = f2bf(acc[n][2] * d) | (f2bf(acc[n][3] * d) << 16);
        unsigned pk2 = f2bf(acc[n][4] * d) | (f2bf(acc[n][5] * d) << 16);
        unsigned pk3 = f2bf(acc[n][6] * d) | (f2bf(acc[n][7] * d) << 16);
        ((uint4*)(xwd + (size_t)node * 16))[t & 3] = make_uint4(pk0, pk1, pk2, pk3);
    }
}

// Layer-1 aggregate FUSED with gemm2: 4 lanes/node gather, x4-unrolled edge
// loop (R18: 4 independent 16B loads in flight per lane -> 2x MLP), register
// accum, then h2wd = (relu(agg*dv + b1) @ W2) * dv via LDS W2 + butterfly.
__global__ __launch_bounds__(256) void aggF_kernel(
        const int* __restrict__ offs, const int* __restrict__ counts,
        const int* __restrict__ csr_src, const float* __restrict__ dinv,
        const unsigned* __restrict__ xwd, const float* __restrict__ b1,
        const float* __restrict__ W2, unsigned* __restrict__ h2wd, int N) {
    __shared__ float ws2[32 * 16];
    for (int i = threadIdx.x; i < 512; i += 256) ws2[i] = W2[i];
    __syncthreads();
    int t = threadIdx.x;
    int q = t & 3;                       // 16B slice
    int node = blockIdx.x * 64 + (t >> 2);
    if (node >= N) return;
    int off = offs[node];
    int deg = counts[node];
    float acc[8];
    {
        uint4 v = ((const uint4*)(xwd + (size_t)node * 16))[q];  // self term
        acc[0] = bflo(v.x); acc[1] = bfhi(v.x);
        acc[2] = bflo(v.y); acc[3] = bfhi(v.y);
        acc[4] = bflo(v.z); acc[5] = bfhi(v.z);
        acc[6] = bflo(v.w); acc[7] = bfhi(v.w);
    }
    int i = 0;
    for (; i + 3 < deg; i += 4) {
        int s0 = csr_src[off + i];
        int s1 = csr_src[off + i + 1];
        int s2 = csr_src[off + i + 2];
        int s3 = csr_src[off + i + 3];
        uint4 v0 = ((const uint4*)(xwd + (size_t)s0 * 16))[q];
        uint4 v1 = ((const uint4*)(xwd + (size_t)s1 * 16))[q];
        uint4 v2 = ((const uint4*)(xwd + (size_t)s2 * 16))[q];
        uint4 v3 = ((const uint4*)(xwd + (size_t)s3 * 16))[q];
        acc[0] += (bflo(v0.x) + bflo(v1.x)) + (bflo(v2.x) + bflo(v3.x));
        acc[1] += (bfhi(v0.x) + bfhi(v1.x)) + (bfhi(v2.x) + bfhi(v3.x));
        acc[2] += (bflo(v0.y) + bflo(v1.y)) + (bflo(v2.y) + bflo(v3.y));
        acc[3] += (bfhi(v0.y) + bfhi(v1.y)) + (bfhi(v2.y) + bfhi(v3.y));
        acc[4] += (bflo(v0.z) + bflo(v1.z)) + (bflo(v2.z) + bflo(v3.z));
        acc[5] += (bfhi(v0.z) + bfhi(v1.z)) + (bfhi(v2.z) + bfhi(v3.z));
        acc[6] += (bflo(v0.w) + bflo(v1.w)) + (bflo(v2.w) + bflo(v3.w));
        acc[7] += (bfhi(v0.w) + bfhi(v1.w)) + (bfhi(v2.w) + bfhi(v3.w));
    }
    for (; i < deg; ++i) {
        int s = csr_src[off + i];
        uint4 v = ((const uint4*)(xwd + (size_t)s * 16))[q];
        acc[0] += bflo(v.x); acc[1] += bfhi(v.x);
        acc[2] += bflo(v.y); acc[3] += bfhi(v.y);
        acc[4] += bflo(v.z); acc[5] += bfhi(v.z);
        acc[6] += bflo(v.w); acc[7] += bfhi(v.w);
    }
    float dv = dinv[node];
    // fused gemm2: lane q owns k = q*8..q*8+7 of the 32-dim hidden vector
    float part[16];
#pragma unroll
    for (int j = 0; j < 16; ++j) part[j] = 0.0f;
    const float* bq = b1 + q * 8;
#pragma unroll
    for (int k = 0; k < 8; ++k) {
        float h = fmaxf(acc[k] * dv + bq[k], 0.0f);
        const float* wr = ws2 + (q * 8 + k) * 16;
        float4 w0 = *(const float4*)(wr);
        float4 w1 = *(const float4*)(wr + 4);
        float4 w2 = *(const float4*)(wr + 8);
        float4 w3 = *(const float4*)(wr + 12);
        part[0]  += h * w0.x; part[1]  += h * w0.y; part[2]  += h * w0.z; part[3]  += h * w0.w;
        part[4]  += h * w1.x; part[5]  += h * w1.y; part[6]  += h * w1.z; part[7]  += h * w1.w;
        part[8]  += h * w2.x; part[9]  += h * w2.y; part[10] += h * w2.z; part[11] += h * w2.w;
        part[12] += h * w3.x; part[13] += h * w3.y; part[14] += h * w3.z; part[15] += h * w3.w;
    }
    // half-exchange butterfly over the quad: 8 + 4 shfl total.
    float p8[8];
#pragma unroll
    for (int j = 0; j < 8; ++j) {
        float send = (q & 1) ? part[j] : part[j + 8];
        float keep = (q & 1) ? part[j + 8] : part[j];
        p8[j] = keep + __shfl_xor(send, 1, 64);
    }
    float p4[4];
#pragma unroll
    for (int j = 0; j < 4; ++j) {
        float send = (q & 2) ? p8[j] : p8[j + 4];
        float keep = (q & 2) ? p8[j + 4] : p8[j];
        p4[j] = keep + __shfl_xor(send, 2, 64);
    }
    unsigned pk0 = f2bf(p4[0] * dv) | (f2bf(p4[1] * dv) << 16);
    unsigned pk1 = f2bf(p4[2] * dv) | (f2bf(p4[3] * dv) << 16);
    int slot = ((q & 1) << 1) | ((q >> 1) & 1);   // col base /4: q0->0 q1->2 q2->1 q3->3
    ((uint2*)(h2wd + (size_t)node * 8))[slot] = make_uint2(pk0, pk1);
}

// Layer-2 aggregate + fused head, 2 lanes/node, x4-unrolled edge loop.
__global__ __launch_bounds__(256) void aggS16f_kernel(
        const int* __restrict__ offs, const int* __restrict__ counts,
        const int* __restrict__ csr_src, const float* __restrict__ dinv,
        const unsigned* __restrict__ h2wd,
        const float* __restrict__ b2, const float* __restrict__ Wf,
        const float* __restrict__ bf, float* __restrict__ out, int N) {
    __shared__ float bs_[16];
    __shared__ float wf_[16];
    __shared__ float bfv;
    int t = threadIdx.x;
    if (t < 16) { bs_[t] = b2[t]; wf_[t] = Wf[t]; }
    if (t == 0) bfv = bf[0];
    __syncthreads();
    int q = t & 1;                        // 16B slice (8 feats)
    int node = blockIdx.x * 128 + (t >> 1);
    if (node >= N) return;
    int off = offs[node];
    int deg = counts[node];
    float acc[8];
    {
        uint4 v = ((const uint4*)(h2wd + (size_t)node * 8))[q];  // self term
        acc[0] = bflo(v.x); acc[1] = bfhi(v.x);
        acc[2] = bflo(v.y); acc[3] = bfhi(v.y);
        acc[4] = bflo(v.z); acc[5] = bfhi(v.z);
        acc[6] = bflo(v.w); acc[7] = bfhi(v.w);
    }
    int i = 0;
    for (; i + 3 < deg; i += 4) {
        int s0 = csr_src[off + i];
        int s1 = csr_src[off + i + 1];
        int s2 = csr_src[off + i + 2];
        int s3 = csr_src[off + i + 3];
        uint4 v0 = ((const uint4*)(h2wd + (size_t)s0 * 8))[q];
        uint4 v1 = ((const uint4*)(h2wd + (size_t)s1 * 8))[q];
        uint4 v2 = ((const uint4*)(h2wd + (size_t)s2 * 8))[q];
        uint4 v3 = ((const uint4*)(h2wd + (size_t)s3 * 8))[q];
        acc[0] += (bflo(v0.x) + bflo(v1.x)) + (bflo(v2.x) + bflo(v3.x));
        acc[1] += (bfhi(v0.x) + bfhi(v1.x)) + (bfhi(v2.x) + bfhi(v3.x));
        acc[2] += (bflo(v0.y) + bflo(v1.y)) + (bflo(v2.y) + bflo(v3.y));
        acc[3] += (bfhi(v0.y) + bfhi(v1.y)) + (bfhi(v2.y) + bfhi(v3.y));
        acc[4] += (bflo(v0.z) + bflo(v1.z)) + (bflo(v2.z) + bflo(v3.z));
        acc[5] += (bfhi(v0.z) + bfhi(v1.z)) + (bfhi(v2.z) + bfhi(v3.z));
        acc[6] += (bflo(v0.w) + bflo(v1.w)) + (bflo(v2.w) + bflo(v3.w));
        acc[7] += (bfhi(v0.w) + bfhi(v1.w)) + (bfhi(v2.w) + bfhi(v3.w));
    }
    for (; i < deg; ++i) {
        int s = csr_src[off + i];
        uint4 v = ((const uint4*)(h2wd + (size_t)s * 8))[q];
        acc[0] += bflo(v.x); acc[1] += bfhi(v.x);
        acc[2] += bflo(v.y); acc[3] += bfhi(v.y);
        acc[4] += bflo(v.z); acc[5] += bfhi(v.z);
        acc[6] += bflo(v.w); acc[7] += bfhi(v.w);
    }
    // fused head: out[node] = relu(acc*dv + b2) . Wf + bf  (pair-split dot)
    float dv = dinv[node];
    const float* bq = bs_ + q * 8;
    const float* wq = wf_ + q * 8;
    float part = 0.f;
#pragma unroll
    for (int k = 0; k < 8; ++k)
        part += fmaxf(acc[k] * dv + bq[k], 0.f) * wq[k];
    part += __shfl_xor(part, 1, 64);  // combine the pair's halves
    if (q == 0) out[node] = part + bfv;
}

extern "C" void kernel_launch(void* const* d_in, const int* in_sizes, int n_in,
                              void* d_out, int out_size, void* d_ws, size_t ws_size,
                              hipStream_t stream) {
    const float* x  = (const float*)d_in[0];
    const int*   ei = (const int*)d_in[1];
    const float* W1 = (const float*)d_in[2];
    const float* b1 = (const float*)d_in[3];
    const float* W2 = (const float*)d_in[4];
    const float* b2 = (const float*)d_in[5];
    const float* Wf = (const float*)d_in[6];
    const float* bf = (const float*)d_in[7];

    int N = in_sizes[0] / 128;
    int E = in_sizes[1] / 2;
    const int* src = ei;       // edge_index[0]
    const int* dst = ei + E;   // edge_index[1]
    int NPB = (N + NBUCK - 1) / NBUCK;  // 196 for N=100k

    // Workspace layout
    size_t Np = ((size_t)N + 3) & ~(size_t)3;
    size_t Ep = ((size_t)E + 3) & ~(size_t)3;
    int* wsI      = (int*)d_ws;
    int* counts   = wsI;                 // Np
    int* offs     = counts + Np;         // Np
    int* bcur     = offs + Np;           // NBUCK
    int* csr_src  = bcur + NBUCK;        // Ep
    float* dinv   = (float*)(csr_src + Ep);      // Np
    unsigned* xwd = (unsigned*)(dinv + Np);      // 16*Np u32 (bf16, 64B rows)
    unsigned* staging = xwd + 16 * Np;           // NBUCK*BCAP u32 = 16.8 MB
    // h2wd (8*N u32 = 3.2 MB) aliases staging: staging written by binA2,
    // read last by buildB; h2wd first written by aggF (later). No overlap.
    unsigned* h2wd = staging;
    float* out    = (float*)d_out;

    int nbG1 = (N + 255) / 256;  // 4 thr/node x 4 nodes/thread
    int nbC  = (E + CHUNK - 1) / CHUNK;
    int nbA32 = (N + 63) / 64;   // 64 nodes/block (4 lanes/node)
    int nbA16 = (N + 127) / 128; // 128 nodes/block (2 lanes/node)

    hipMemsetAsync(bcur, 0, NBUCK * sizeof(int), stream);
    binA2_kernel<<<nbC, 512, 0, stream>>>(src, dst, bcur, staging, E, NPB);
    buildB_kernel<<<NBUCK, 512, 0, stream>>>(bcur, staging, offs, counts,
                                             dinv, csr_src, N, NPB);
    gemm1_kernel<<<nbG1, 256, 0, stream>>>(x, W1, dinv, xwd, N);
    aggF_kernel<<<nbA32, 256, 0, stream>>>(offs, counts, csr_src, dinv, xwd,
                                           b1, W2, h2wd, N);
    aggS16f_kernel<<<nbA16, 256, 0, stream>>>(offs, counts, csr_src, dinv, h2wd,
                                              b2, Wf, bf, out, N);
}

// Round 5
// 251.234 us; speedup vs baseline: 3.9951x; 1.0084x over previous
//
#include <hip/hip_runtime.h>

// GCN forward via two-level CSR build + gather aggregation.
// Lessons ledger:
//   R4/R9:  atomic float aggregation (global) loses 5-10x to register gather.
//   R15:    ...and LDS float atomics lose too (591us). Register accum only.
//   R17:    scattered 4B global writes forbidden (15x partial-line write
//           amplification across 8 non-coherent L2s -> 300us scatter).
//   R13/18: gather is bound by random 64B-line fetch rate (~2.5TB/s): x4
//           unroll bought only 6% (53.5->50.2); aggF FETCH 119MB/50us is a
//           structural floor while xwd (6.4MB) > 4MB per-XCD L2.
//   R19 (this round): build+gemm1 were the hidden ~200us: gemm1 at 1.5
//           waves/SIMD (4-node blocking cut the grid 4x); build kernels
//           barrier-heavy (ladder scans, redundant per-block bucket-base
//           scan) and double-read their inputs. Fixes: 2-node gemm1 (782
//           blocks), wave scans (shfl), register staging, hoisted bbase.
// Pipeline:
//   binA2: per-block LDS radix partition -> 512 dst-range buckets.
//   bbase: one-block exclusive scan of bucket sizes.
//   buildB: per-bucket hist+scan -> counts/offs/dinv + CSR placement.
//   gemm1: xwd = (x@W1)*dinv, bf16 64B rows, 4 thr/node x 2 nodes/thr.
//   aggF: layer-1 gather (4 lanes/node, x4 unroll) fused with gemm2 -> h2wd.
//   aggS16f: layer-2 gather (2 lanes/node, x4 unroll) + fused head -> out.

#define TPB 256
#define NBUCK 512
#define BCAP 8192    // bucket capacity; mean ~6272, sd ~79 -> 24 sigma margin
#define CHUNK 4096   // edges per binA2 block -> 782 blocks, ~4/CU by LDS

__device__ __forceinline__ unsigned f2bf(float f) {  // RNE fp32->bf16
    unsigned u = __float_as_uint(f);
    return (u + 0x7FFFu + ((u >> 16) & 1u)) >> 16;
}
__device__ __forceinline__ float bflo(unsigned u) { return __uint_as_float(u << 16); }
__device__ __forceinline__ float bfhi(unsigned u) { return __uint_as_float(u & 0xFFFF0000u); }

// Exclusive scan over 512 values (one per thread) using wave shfl scans.
// 2 barriers total (vs 18 for the ladder). wsum: dedicated LDS int[8].
__device__ __forceinline__ int excl_scan_512(int v, int* wsum, int tid) {
    int lane = tid & 63, wv = tid >> 6;
    int x = v;
#pragma unroll
    for (int d = 1; d < 64; d <<= 1) {
        int y = __shfl_up(x, d, 64);
        if (lane >= d) x += y;
    }
    if (lane == 63) wsum[wv] = x;          // inclusive wave sum
    __syncthreads();
    if (tid < 64) {
        int s = (lane < 8) ? wsum[lane] : 0;
#pragma unroll
        for (int d = 1; d < 8; d <<= 1) {
            int y = __shfl_up(s, d, 64);
            if (lane >= d) s += y;
        }
        if (lane < 8) wsum[lane] = s;      // inclusive across waves
    }
    __syncthreads();
    int base = (wv > 0) ? wsum[wv - 1] : 0;
    return base + x - v;                   // exclusive prefix
}

// Phase A: block-local radix partition, bulk append to global staging.
// Register-staged edges: src/dst read exactly once from global.
__global__ __launch_bounds__(512) void binA2_kernel(
        const int* __restrict__ src, const int* __restrict__ dst,
        int* __restrict__ bcur, unsigned* __restrict__ staging, int E, int NPB) {
    __shared__ unsigned packed[CHUNK];         // 16 KB
    __shared__ unsigned short buckb[CHUNK];    // 8 KB
    __shared__ int hist[NBUCK];                // 2 KB each
    __shared__ int lstart[NBUCK];
    __shared__ int lcur[NBUCK];
    __shared__ int gbase[NBUCK];
    __shared__ int wsum[8];
    int tid = threadIdx.x;
    int start = blockIdx.x * CHUNK;
    int sz = min(CHUNK, E - start);

    unsigned dreg[8], sreg[8];
    hist[tid] = 0;
#pragma unroll
    for (int c = 0; c < 8; ++c) {              // compile-time idx -> VGPRs
        int i = tid + c * 512;
        if (i < sz) {
            dreg[c] = (unsigned)dst[start + i];
            sreg[c] = (unsigned)src[start + i];
        } else {
            dreg[c] = 0xFFFFFFFFu;             // sentinel (real d < N)
        }
    }
    __syncthreads();
#pragma unroll
    for (int c = 0; c < 8; ++c)
        if (dreg[c] != 0xFFFFFFFFu) atomicAdd(&hist[dreg[c] / (unsigned)NPB], 1);
    __syncthreads();
    int v = hist[tid];
    int excl = excl_scan_512(v, wsum, tid);
    lstart[tid] = excl;
    lcur[tid] = 0;
    gbase[tid] = atomicAdd(&bcur[tid], v);     // one reservation per (block,bucket)
    __syncthreads();
#pragma unroll
    for (int c = 0; c < 8; ++c) {
        if (dreg[c] == 0xFFFFFFFFu) continue;
        unsigned d = dreg[c];
        unsigned b = d / (unsigned)NPB;
        unsigned loc = d - b * (unsigned)NPB;
        int pos = atomicAdd(&lcur[b], 1);
        int si = lstart[b] + pos;
        packed[si] = (loc << 20) | sreg[c];    // loc<=195 (12b), src<2^17
        buckb[si] = (unsigned short)b;
    }
    __syncthreads();
    for (int i = tid; i < sz; i += 512) {      // bucket-contiguous bulk write
        unsigned b = buckb[i];
        int dsti = gbase[b] + (i - lstart[b]);
        if (dsti < BCAP)
            staging[(size_t)b * BCAP + dsti] = packed[i];
    }
}

// One block: exclusive prefix of clamped bucket sizes -> bbase[NBUCK].
// Hoisted out of buildB (was redundantly recomputed in all 512 blocks).
__global__ __launch_bounds__(512) void bbase_kernel(
        const int* __restrict__ bcur, int* __restrict__ bbase) {
    __shared__ int wsum[8];
    int tid = threadIdx.x;
    int v = min(bcur[tid], BCAP);
    bbase[tid] = excl_scan_512(v, wsum, tid);
}

// Phase B: one block per bucket; register-staged (staging read once);
// hist + wave-scan -> counts/offs/dinv + CSR placement.
__global__ __launch_bounds__(512) void buildB_kernel(
        const int* __restrict__ bcur, const int* __restrict__ bbase,
        const unsigned* __restrict__ staging,
        int* __restrict__ offs, int* __restrict__ counts,
        float* __restrict__ dinv, int* __restrict__ csr_src,
        int N, int NPB) {
    __shared__ int hist[512];
    __shared__ int cur[512];
    __shared__ int wsum[8];
    int b = blockIdx.x;
    int tid = threadIdx.x;
    int sz = min(bcur[b], BCAP);
    int base = bbase[b];
    int n0 = b * NPB;
    int nn = min(NPB, N - n0);
    const unsigned* se = staging + (size_t)b * BCAP;

    unsigned preg[16];                         // BCAP/512 = 16 covers any sz
    hist[tid] = 0;
#pragma unroll
    for (int c = 0; c < 16; ++c) {
        int i = tid + c * 512;
        preg[c] = (i < sz) ? se[i] : 0xFFFFFFFFu;  // sentinel: loc field 4095
    }
    __syncthreads();
#pragma unroll
    for (int c = 0; c < 16; ++c)
        if (preg[c] != 0xFFFFFFFFu) atomicAdd(&hist[preg[c] >> 20], 1);
    __syncthreads();
    int h = hist[tid];
    int excl = excl_scan_512(h, wsum, tid);
    cur[tid] = excl;
    if (tid < nn) {
        int node = n0 + tid;
        offs[node] = base + excl;
        counts[node] = h;
        dinv[node] = rsqrtf((float)(h + 1));   // +1 self-loop
    }
    __syncthreads();
#pragma unroll
    for (int c = 0; c < 16; ++c) {
        unsigned p = preg[c];
        if (p == 0xFFFFFFFFu) continue;
        int pos = atomicAdd(&cur[p >> 20], 1);
        csr_src[base + pos] = (int)(p & 0xFFFFFu);
    }
}

// xwd(bf16) = (x @ W1) * dinv[node].  4 threads/node x 8 cols x 2 nodes/thr.
// R19: 2 nodes/thread (not 4) -> grid 782, ~3 blocks/CU, 12 waves/CU; LDS
// W-traffic 800MB (~12us at 69TB/s) vs latency exposure at 1.5 waves/SIMD.
__global__ __launch_bounds__(256) void gemm1_kernel(
        const float* __restrict__ x, const float* __restrict__ W1,
        const float* __restrict__ dinv, unsigned* __restrict__ xwd, int N) {
    __shared__ float ws_[128 * 32];
    for (int i = threadIdx.x; i < 128 * 32; i += 256) ws_[i] = W1[i];
    __syncthreads();
    int t = threadIdx.x;
    int jq = (t & 3) * 8;  // 8 output cols
    int n0 = blockIdx.x * 128 + (t >> 2) * 2;
    if (n0 >= N) return;
    int nc0 = min(n0 + 0, N - 1);
    int nc1 = min(n0 + 1, N - 1);
    const float4* xr0 = (const float4*)(x + (size_t)nc0 * 128);
    const float4* xr1 = (const float4*)(x + (size_t)nc1 * 128);
    float acc[2][8];
#pragma unroll
    for (int n = 0; n < 2; ++n)
#pragma unroll
        for (int j = 0; j < 8; ++j) acc[n][j] = 0.0f;
#pragma unroll 2
    for (int k4 = 0; k4 < 32; ++k4) {
        const float* wb = ws_ + (k4 * 4) * 32 + jq;
        float4 a0 = *(const float4*)(wb);
        float4 a1 = *(const float4*)(wb + 4);
        float4 b0 = *(const float4*)(wb + 32);
        float4 b1v = *(const float4*)(wb + 36);
        float4 c0 = *(const float4*)(wb + 64);
        float4 c1 = *(const float4*)(wb + 68);
        float4 d0 = *(const float4*)(wb + 96);
        float4 d1 = *(const float4*)(wb + 100);
        float4 xv0 = xr0[k4];
        float4 xv1 = xr1[k4];
#pragma unroll
        for (int n = 0; n < 2; ++n) {
            float4 xv = (n == 0) ? xv0 : xv1;
            acc[n][0] += xv.x * a0.x + xv.y * b0.x + xv.z * c0.x + xv.w * d0.x;
            acc[n][1] += xv.x * a0.y + xv.y * b0.y + xv.z * c0.y + xv.w * d0.y;
            acc[n][2] += xv.x * a0.z + xv.y * b0.z + xv.z * c0.z + xv.w * d0.z;
            acc[n][3] += xv.x * a0.w + xv.y * b0.w + xv.z * c0.w + xv.w * d0.w;
            acc[n][4] += xv.x * a1.x + xv.y * b1v.x + xv.z * c1.x + xv.w * d1.x;
            acc[n][5] += xv.x * a1.y + xv.y * b1v.y + xv.z * c1.y + xv.w * d1.y;
            acc[n][6] += xv.x * a1.z + xv.y * b1v.z + xv.z * c1.z + xv.w * d1.z;
            acc[n][7] += xv.x * a1.w + xv.y * b1v.w + xv.z * c1.w + xv.w * d1.w;
        }
    }
#pragma unroll
    for (int n = 0; n < 2; ++n) {
        int node = n0 + n;
        if (node >= N) break;
        float d = dinv[node];
        unsigned pk0 = f2bf(acc[n][0] * d) | (f2bf(acc[n][1] * d) << 16);
        unsigned pk1 = f2bf(acc[n][2] * d) | (f2bf(acc[n][3] * d) << 16);
        unsigned pk2 = f2bf(acc[n][4] * d) | (f2bf(acc[n][5] * d) << 16);
        unsigned pk3 = f2bf(acc[n][6] * d) | (f2bf(acc[n][7] * d) << 16);
        ((uint4*)(xwd + (size_t)node * 16))[t & 3] = make_uint4(pk0, pk1, pk2, pk3);
    }
}

// Layer-1 aggregate FUSED with gemm2: 4 lanes/node gather, x4-unrolled edge
// loop, register accum, then h2wd = (relu(agg*dv + b1) @ W2) * dv.
__global__ __launch_bounds__(256) void aggF_kernel(
        const int* __restrict__ offs, const int* __restrict__ counts,
        const int* __restrict__ csr_src, const float* __restrict__ dinv,
        const unsigned* __restrict__ xwd, const float* __restrict__ b1,
        const float* __restrict__ W2, unsigned* __restrict__ h2wd, int N) {
    __shared__ float ws2[32 * 16];
    for (int i = threadIdx.x; i < 512; i += 256) ws2[i] = W2[i];
    __syncthreads();
    int t = threadIdx.x;
    int q = t & 3;                       // 16B slice
    int node = blockIdx.x * 64 + (t >> 2);
    if (node >= N) return;
    int off = offs[node];
    int deg = counts[node];
    float acc[8];
    {
        uint4 v = ((const uint4*)(xwd + (size_t)node * 16))[q];  // self term
        acc[0] = bflo(v.x); acc[1] = bfhi(v.x);
        acc[2] = bflo(v.y); acc[3] = bfhi(v.y);
        acc[4] = bflo(v.z); acc[5] = bfhi(v.z);
        acc[6] = bflo(v.w); acc[7] = bfhi(v.w);
    }
    int i = 0;
    for (; i + 3 < deg; i += 4) {
        int s0 = csr_src[off + i];
        int s1 = csr_src[off + i + 1];
        int s2 = csr_src[off + i + 2];
        int s3 = csr_src[off + i + 3];
        uint4 v0 = ((const uint4*)(xwd + (size_t)s0 * 16))[q];
        uint4 v1 = ((const uint4*)(xwd + (size_t)s1 * 16))[q];
        uint4 v2 = ((const uint4*)(xwd + (size_t)s2 * 16))[q];
        uint4 v3 = ((const uint4*)(xwd + (size_t)s3 * 16))[q];
        acc[0] += (bflo(v0.x) + bflo(v1.x)) + (bflo(v2.x) + bflo(v3.x));
        acc[1] += (bfhi(v0.x) + bfhi(v1.x)) + (bfhi(v2.x) + bfhi(v3.x));
        acc[2] += (bflo(v0.y) + bflo(v1.y)) + (bflo(v2.y) + bflo(v3.y));
        acc[3] += (bfhi(v0.y) + bfhi(v1.y)) + (bfhi(v2.y) + bfhi(v3.y));
        acc[4] += (bflo(v0.z) + bflo(v1.z)) + (bflo(v2.z) + bflo(v3.z));
        acc[5] += (bfhi(v0.z) + bfhi(v1.z)) + (bfhi(v2.z) + bfhi(v3.z));
        acc[6] += (bflo(v0.w) + bflo(v1.w)) + (bflo(v2.w) + bflo(v3.w));
        acc[7] += (bfhi(v0.w) + bfhi(v1.w)) + (bfhi(v2.w) + bfhi(v3.w));
    }
    for (; i < deg; ++i) {
        int s = csr_src[off + i];
        uint4 v = ((const uint4*)(xwd + (size_t)s * 16))[q];
        acc[0] += bflo(v.x); acc[1] += bfhi(v.x);
        acc[2] += bflo(v.y); acc[3] += bfhi(v.y);
        acc[4] += bflo(v.z); acc[5] += bfhi(v.z);
        acc[6] += bflo(v.w); acc[7] += bfhi(v.w);
    }
    float dv = dinv[node];
    // fused gemm2: lane q owns k = q*8..q*8+7 of the 32-dim hidden vector
    float part[16];
#pragma unroll
    for (int j = 0; j < 16; ++j) part[j] = 0.0f;
    const float* bq = b1 + q * 8;
#pragma unroll
    for (int k = 0; k < 8; ++k) {
        float h = fmaxf(acc[k] * dv + bq[k], 0.0f);
        const float* wr = ws2 + (q * 8 + k) * 16;
        float4 w0 = *(const float4*)(wr);
        float4 w1 = *(const float4*)(wr + 4);
        float4 w2 = *(const float4*)(wr + 8);
        float4 w3 = *(const float4*)(wr + 12);
        part[0]  += h * w0.x; part[1]  += h * w0.y; part[2]  += h * w0.z; part[3]  += h * w0.w;
        part[4]  += h * w1.x; part[5]  += h * w1.y; part[6]  += h * w1.z; part[7]  += h * w1.w;
        part[8]  += h * w2.x; part[9]  += h * w2.y; part[10] += h * w2.z; part[11] += h * w2.w;
        part[12] += h * w3.x; part[13] += h * w3.y; part[14] += h * w3.z; part[15] += h * w3.w;
    }
    // half-exchange butterfly over the quad: 8 + 4 shfl total.
    float p8[8];
#pragma unroll
    for (int j = 0; j < 8; ++j) {
        float send = (q & 1) ? part[j] : part[j + 8];
        float keep = (q & 1) ? part[j + 8] : part[j];
        p8[j] = keep + __shfl_xor(send, 1, 64);
    }
    float p4[4];
#pragma unroll
    for (int j = 0; j < 4; ++j) {
        float send = (q & 2) ? p8[j] : p8[j + 4];
        float keep = (q & 2) ? p8[j + 4] : p8[j];
        p4[j] = keep + __shfl_xor(send, 2, 64);
    }
    unsigned pk0 = f2bf(p4[0] * dv) | (f2bf(p4[1] * dv) << 16);
    unsigned pk1 = f2bf(p4[2] * dv) | (f2bf(p4[3] * dv) << 16);
    int slot = ((q & 1) << 1) | ((q >> 1) & 1);   // col base /4: q0->0 q1->2 q2->1 q3->3
    ((uint2*)(h2wd + (size_t)node * 8))[slot] = make_uint2(pk0, pk1);
}

// Layer-2 aggregate + fused head, 2 lanes/node, x4-unrolled edge loop.
__global__ __launch_bounds__(256) void aggS16f_kernel(
        const int* __restrict__ offs, const int* __restrict__ counts,
        const int* __restrict__ csr_src, const float* __restrict__ dinv,
        const unsigned* __restrict__ h2wd,
        const float* __restrict__ b2, const float* __restrict__ Wf,
        const float* __restrict__ bf, float* __restrict__ out, int N) {
    __shared__ float bs_[16];
    __shared__ float wf_[16];
    __shared__ float bfv;
    int t = threadIdx.x;
    if (t < 16) { bs_[t] = b2[t]; wf_[t] = Wf[t]; }
    if (t == 0) bfv = bf[0];
    __syncthreads();
    int q = t & 1;                        // 16B slice (8 feats)
    int node = blockIdx.x * 128 + (t >> 1);
    if (node >= N) return;
    int off = offs[node];
    int deg = counts[node];
    float acc[8];
    {
        uint4 v = ((const uint4*)(h2wd + (size_t)node * 8))[q];  // self term
        acc[0] = bflo(v.x); acc[1] = bfhi(v.x);
        acc[2] = bflo(v.y); acc[3] = bfhi(v.y);
        acc[4] = bflo(v.z); acc[5] = bfhi(v.z);
        acc[6] = bflo(v.w); acc[7] = bfhi(v.w);
    }
    int i = 0;
    for (; i + 3 < deg; i += 4) {
        int s0 = csr_src[off + i];
        int s1 = csr_src[off + i + 1];
        int s2 = csr_src[off + i + 2];
        int s3 = csr_src[off + i + 3];
        uint4 v0 = ((const uint4*)(h2wd + (size_t)s0 * 8))[q];
        uint4 v1 = ((const uint4*)(h2wd + (size_t)s1 * 8))[q];
        uint4 v2 = ((const uint4*)(h2wd + (size_t)s2 * 8))[q];
        uint4 v3 = ((const uint4*)(h2wd + (size_t)s3 * 8))[q];
        acc[0] += (bflo(v0.x) + bflo(v1.x)) + (bflo(v2.x) + bflo(v3.x));
        acc[1] += (bfhi(v0.x) + bfhi(v1.x)) + (bfhi(v2.x) + bfhi(v3.x));
        acc[2] += (bflo(v0.y) + bflo(v1.y)) + (bflo(v2.y) + bflo(v3.y));
        acc[3] += (bfhi(v0.y) + bfhi(v1.y)) + (bfhi(v2.y) + bfhi(v3.y));
        acc[4] += (bflo(v0.z) + bflo(v1.z)) + (bflo(v2.z) + bflo(v3.z));
        acc[5] += (bfhi(v0.z) + bfhi(v1.z)) + (bfhi(v2.z) + bfhi(v3.z));
        acc[6] += (bflo(v0.w) + bflo(v1.w)) + (bflo(v2.w) + bflo(v3.w));
        acc[7] += (bfhi(v0.w) + bfhi(v1.w)) + (bfhi(v2.w) + bfhi(v3.w));
    }
    for (; i < deg; ++i) {
        int s = csr_src[off + i];
        uint4 v = ((const uint4*)(h2wd + (size_t)s * 8))[q];
        acc[0] += bflo(v.x); acc[1] += bfhi(v.x);
        acc[2] += bflo(v.y); acc[3] += bfhi(v.y);
        acc[4] += bflo(v.z); acc[5] += bfhi(v.z);
        acc[6] += bflo(v.w); acc[7] += bfhi(v.w);
    }
    // fused head: out[node] = relu(acc*dv + b2) . Wf + bf  (pair-split dot)
    float dv = dinv[node];
    const float* bq = bs_ + q * 8;
    const float* wq = wf_ + q * 8;
    float part = 0.f;
#pragma unroll
    for (int k = 0; k < 8; ++k)
        part += fmaxf(acc[k] * dv + bq[k], 0.f) * wq[k];
    part += __shfl_xor(part, 1, 64);  // combine the pair's halves
    if (q == 0) out[node] = part + bfv;
}

extern "C" void kernel_launch(void* const* d_in, const int* in_sizes, int n_in,
                              void* d_out, int out_size, void* d_ws, size_t ws_size,
                              hipStream_t stream) {
    const float* x  = (const float*)d_in[0];
    const int*   ei = (const int*)d_in[1];
    const float* W1 = (const float*)d_in[2];
    const float* b1 = (const float*)d_in[3];
    const float* W2 = (const float*)d_in[4];
    const float* b2 = (const float*)d_in[5];
    const float* Wf = (const float*)d_in[6];
    const float* bf = (const float*)d_in[7];

    int N = in_sizes[0] / 128;
    int E = in_sizes[1] / 2;
    const int* src = ei;       // edge_index[0]
    const int* dst = ei + E;   // edge_index[1]
    int NPB = (N + NBUCK - 1) / NBUCK;  // 196 for N=100k

    // Workspace layout
    size_t Np = ((size_t)N + 3) & ~(size_t)3;
    size_t Ep = ((size_t)E + 3) & ~(size_t)3;
    int* wsI      = (int*)d_ws;
    int* counts   = wsI;                 // Np
    int* offs     = counts + Np;         // Np
    int* bcur     = offs + Np;           // NBUCK
    int* bbase    = bcur + NBUCK;        // NBUCK
    int* csr_src  = bbase + NBUCK;       // Ep
    float* dinv   = (float*)(csr_src + Ep);      // Np
    unsigned* xwd = (unsigned*)(dinv + Np);      // 16*Np u32 (bf16, 64B rows)
    unsigned* staging = xwd + 16 * Np;           // NBUCK*BCAP u32 = 16.8 MB
    // h2wd (8*N u32 = 3.2 MB) aliases staging: staging written by binA2,
    // read last by buildB; h2wd first written by aggF (later). No overlap.
    unsigned* h2wd = staging;
    float* out    = (float*)d_out;

    int nbC  = (E + CHUNK - 1) / CHUNK;  // 782
    int nbG1 = (N + 127) / 128;          // 782 (2 nodes/thread)
    int nbA32 = (N + 63) / 64;   // 64 nodes/block (4 lanes/node)
    int nbA16 = (N + 127) / 128; // 128 nodes/block (2 lanes/node)

    hipMemsetAsync(bcur, 0, NBUCK * sizeof(int), stream);
    binA2_kernel<<<nbC, 512, 0, stream>>>(src, dst, bcur, staging, E, NPB);
    bbase_kernel<<<1, 512, 0, stream>>>(bcur, bbase);
    buildB_kernel<<<NBUCK, 512, 0, stream>>>(bcur, bbase, staging, offs, counts,
                                             dinv, csr_src, N, NPB);
    gemm1_kernel<<<nbG1, 256, 0, stream>>>(x, W1, dinv, xwd, N);
    aggF_kernel<<<nbA32, 256, 0, stream>>>(offs, counts, csr_src, dinv, xwd,
                                           b1, W2, h2wd, N);
    aggS16f_kernel<<<nbA16, 256, 0, stream>>>(offs, counts, csr_src, dinv, h2wd,
                                              b2, Wf, bf, out, N);
}

// Round 6
// 244.745 us; speedup vs baseline: 4.1010x; 1.0265x over previous
//
#include <hip/hip_runtime.h>

// GCN forward via two-level CSR build + gather aggregation.
// Lessons ledger:
//   R4/R9:  atomic float aggregation (global) loses 5-10x to register gather.
//   R15:    ...and LDS float atomics lose too (591us). Register accum only.
//   R17:    scattered 4B global writes forbidden (15x partial-line write
//           amplification across 8 non-coherent L2s -> 300us scatter).
//   R13/18: gather: x4 unroll bought 6% (53.5->50.2).
//   R19:    build-kernel micro-opts (barriers, staging, occupancy) were all
//           null: binA2/buildB/gemm1 are bound by something not yet measured.
//           Stop predicting invisible kernels; only touch what counters show.
//   R20 (this round): aggF counters (VALU 18%, HBM 31%, occ 29%) => latency
//           bound on the serial csr->gather chain (~800cy per 4 edges). Fix:
//           x8 gather batches + next-batch csr index prefetch so index
//           latency hides under gathers and 8 lines/quad stay in flight.
// Pipeline:
//   binA2: per-block LDS radix partition -> 512 dst-range buckets.
//   bbase: one-block exclusive scan of bucket sizes.
//   buildB: per-bucket hist+scan -> counts/offs/dinv + CSR placement.
//   gemm1: xwd = (x@W1)*dinv, bf16 64B rows, 4 thr/node x 2 nodes/thr.
//   aggF: layer-1 gather (4 lanes/node, x8 pipelined) fused with gemm2 -> h2wd.
//   aggS16f: layer-2 gather (2 lanes/node, x8 pipelined) + fused head -> out.

#define TPB 256
#define NBUCK 512
#define BCAP 8192    // bucket capacity; mean ~6272, sd ~79 -> 24 sigma margin
#define CHUNK 4096   // edges per binA2 block -> 782 blocks, ~4/CU by LDS

__device__ __forceinline__ unsigned f2bf(float f) {  // RNE fp32->bf16
    unsigned u = __float_as_uint(f);
    return (u + 0x7FFFu + ((u >> 16) & 1u)) >> 16;
}
__device__ __forceinline__ float bflo(unsigned u) { return __uint_as_float(u << 16); }
__device__ __forceinline__ float bfhi(unsigned u) { return __uint_as_float(u & 0xFFFF0000u); }

// Exclusive scan over 512 values (one per thread) using wave shfl scans.
__device__ __forceinline__ int excl_scan_512(int v, int* wsum, int tid) {
    int lane = tid & 63, wv = tid >> 6;
    int x = v;
#pragma unroll
    for (int d = 1; d < 64; d <<= 1) {
        int y = __shfl_up(x, d, 64);
        if (lane >= d) x += y;
    }
    if (lane == 63) wsum[wv] = x;          // inclusive wave sum
    __syncthreads();
    if (tid < 64) {
        int s = (lane < 8) ? wsum[lane] : 0;
#pragma unroll
        for (int d = 1; d < 8; d <<= 1) {
            int y = __shfl_up(s, d, 64);
            if (lane >= d) s += y;
        }
        if (lane < 8) wsum[lane] = s;      // inclusive across waves
    }
    __syncthreads();
    int base = (wv > 0) ? wsum[wv - 1] : 0;
    return base + x - v;                   // exclusive prefix
}

// Phase A: block-local radix partition, bulk append to global staging.
__global__ __launch_bounds__(512) void binA2_kernel(
        const int* __restrict__ src, const int* __restrict__ dst,
        int* __restrict__ bcur, unsigned* __restrict__ staging, int E, int NPB) {
    __shared__ unsigned packed[CHUNK];         // 16 KB
    __shared__ unsigned short buckb[CHUNK];    // 8 KB
    __shared__ int hist[NBUCK];                // 2 KB each
    __shared__ int lstart[NBUCK];
    __shared__ int lcur[NBUCK];
    __shared__ int gbase[NBUCK];
    __shared__ int wsum[8];
    int tid = threadIdx.x;
    int start = blockIdx.x * CHUNK;
    int sz = min(CHUNK, E - start);

    unsigned dreg[8], sreg[8];
    hist[tid] = 0;
#pragma unroll
    for (int c = 0; c < 8; ++c) {              // compile-time idx -> VGPRs
        int i = tid + c * 512;
        if (i < sz) {
            dreg[c] = (unsigned)dst[start + i];
            sreg[c] = (unsigned)src[start + i];
        } else {
            dreg[c] = 0xFFFFFFFFu;             // sentinel (real d < N)
        }
    }
    __syncthreads();
#pragma unroll
    for (int c = 0; c < 8; ++c)
        if (dreg[c] != 0xFFFFFFFFu) atomicAdd(&hist[dreg[c] / (unsigned)NPB], 1);
    __syncthreads();
    int v = hist[tid];
    int excl = excl_scan_512(v, wsum, tid);
    lstart[tid] = excl;
    lcur[tid] = 0;
    gbase[tid] = atomicAdd(&bcur[tid], v);     // one reservation per (block,bucket)
    __syncthreads();
#pragma unroll
    for (int c = 0; c < 8; ++c) {
        if (dreg[c] == 0xFFFFFFFFu) continue;
        unsigned d = dreg[c];
        unsigned b = d / (unsigned)NPB;
        unsigned loc = d - b * (unsigned)NPB;
        int pos = atomicAdd(&lcur[b], 1);
        int si = lstart[b] + pos;
        packed[si] = (loc << 20) | sreg[c];    // loc<=195 (12b), src<2^17
        buckb[si] = (unsigned short)b;
    }
    __syncthreads();
    for (int i = tid; i < sz; i += 512) {      // bucket-contiguous bulk write
        unsigned b = buckb[i];
        int dsti = gbase[b] + (i - lstart[b]);
        if (dsti < BCAP)
            staging[(size_t)b * BCAP + dsti] = packed[i];
    }
}

// One block: exclusive prefix of clamped bucket sizes -> bbase[NBUCK].
__global__ __launch_bounds__(512) void bbase_kernel(
        const int* __restrict__ bcur, int* __restrict__ bbase) {
    __shared__ int wsum[8];
    int tid = threadIdx.x;
    int v = min(bcur[tid], BCAP);
    bbase[tid] = excl_scan_512(v, wsum, tid);
}

// Phase B: one block per bucket; register-staged; hist + wave-scan ->
// counts/offs/dinv + CSR placement.
__global__ __launch_bounds__(512) void buildB_kernel(
        const int* __restrict__ bcur, const int* __restrict__ bbase,
        const unsigned* __restrict__ staging,
        int* __restrict__ offs, int* __restrict__ counts,
        float* __restrict__ dinv, int* __restrict__ csr_src,
        int N, int NPB) {
    __shared__ int hist[512];
    __shared__ int cur[512];
    __shared__ int wsum[8];
    int b = blockIdx.x;
    int tid = threadIdx.x;
    int sz = min(bcur[b], BCAP);
    int base = bbase[b];
    int n0 = b * NPB;
    int nn = min(NPB, N - n0);
    const unsigned* se = staging + (size_t)b * BCAP;

    unsigned preg[16];                         // BCAP/512 = 16 covers any sz
    hist[tid] = 0;
#pragma unroll
    for (int c = 0; c < 16; ++c) {
        int i = tid + c * 512;
        preg[c] = (i < sz) ? se[i] : 0xFFFFFFFFu;
    }
    __syncthreads();
#pragma unroll
    for (int c = 0; c < 16; ++c)
        if (preg[c] != 0xFFFFFFFFu) atomicAdd(&hist[preg[c] >> 20], 1);
    __syncthreads();
    int h = hist[tid];
    int excl = excl_scan_512(h, wsum, tid);
    cur[tid] = excl;
    if (tid < nn) {
        int node = n0 + tid;
        offs[node] = base + excl;
        counts[node] = h;
        dinv[node] = rsqrtf((float)(h + 1));   // +1 self-loop
    }
    __syncthreads();
#pragma unroll
    for (int c = 0; c < 16; ++c) {
        unsigned p = preg[c];
        if (p == 0xFFFFFFFFu) continue;
        int pos = atomicAdd(&cur[p >> 20], 1);
        csr_src[base + pos] = (int)(p & 0xFFFFFu);
    }
}

// xwd(bf16) = (x @ W1) * dinv[node].  4 threads/node x 8 cols x 2 nodes/thr.
__global__ __launch_bounds__(256) void gemm1_kernel(
        const float* __restrict__ x, const float* __restrict__ W1,
        const float* __restrict__ dinv, unsigned* __restrict__ xwd, int N) {
    __shared__ float ws_[128 * 32];
    for (int i = threadIdx.x; i < 128 * 32; i += 256) ws_[i] = W1[i];
    __syncthreads();
    int t = threadIdx.x;
    int jq = (t & 3) * 8;  // 8 output cols
    int n0 = blockIdx.x * 128 + (t >> 2) * 2;
    if (n0 >= N) return;
    int nc0 = min(n0 + 0, N - 1);
    int nc1 = min(n0 + 1, N - 1);
    const float4* xr0 = (const float4*)(x + (size_t)nc0 * 128);
    const float4* xr1 = (const float4*)(x + (size_t)nc1 * 128);
    float acc[2][8];
#pragma unroll
    for (int n = 0; n < 2; ++n)
#pragma unroll
        for (int j = 0; j < 8; ++j) acc[n][j] = 0.0f;
#pragma unroll 2
    for (int k4 = 0; k4 < 32; ++k4) {
        const float* wb = ws_ + (k4 * 4) * 32 + jq;
        float4 a0 = *(const float4*)(wb);
        float4 a1 = *(const float4*)(wb + 4);
        float4 b0 = *(const float4*)(wb + 32);
        float4 b1v = *(const float4*)(wb + 36);
        float4 c0 = *(const float4*)(wb + 64);
        float4 c1 = *(const float4*)(wb + 68);
        float4 d0 = *(const float4*)(wb + 96);
        float4 d1 = *(const float4*)(wb + 100);
        float4 xv0 = xr0[k4];
        float4 xv1 = xr1[k4];
#pragma unroll
        for (int n = 0; n < 2; ++n) {
            float4 xv = (n == 0) ? xv0 : xv1;
            acc[n][0] += xv.x * a0.x + xv.y * b0.x + xv.z * c0.x + xv.w * d0.x;
            acc[n][1] += xv.x * a0.y + xv.y * b0.y + xv.z * c0.y + xv.w * d0.y;
            acc[n][2] += xv.x * a0.z + xv.y * b0.z + xv.z * c0.z + xv.w * d0.z;
            acc[n][3] += xv.x * a0.w + xv.y * b0.w + xv.z * c0.w + xv.w * d0.w;
            acc[n][4] += xv.x * a1.x + xv.y * b1v.x + xv.z * c1.x + xv.w * d1.x;
            acc[n][5] += xv.x * a1.y + xv.y * b1v.y + xv.z * c1.y + xv.w * d1.y;
            acc[n][6] += xv.x * a1.z + xv.y * b1v.z + xv.z * c1.z + xv.w * d1.z;
            acc[n][7] += xv.x * a1.w + xv.y * b1v.w + xv.z * c1.w + xv.w * d1.w;
        }
    }
#pragma unroll
    for (int n = 0; n < 2; ++n) {
        int node = n0 + n;
        if (node >= N) break;
        float d = dinv[node];
        unsigned pk0 = f2bf(acc[n][0] * d) | (f2bf(acc[n][1] * d) << 16);
        unsigned pk1 = f2bf(acc[n][2] * d) | (f2bf(acc[n][3] * d) << 16);
        unsigned pk2 = f2bf(acc[n][4] * d) | (f2bf(acc[n][5] * d) << 16);
        unsigned pk3 = f2bf(acc[n][6] * d) | (f2bf(acc[n][7] * d) << 16);
        ((uint4*)(xwd + (size_t)node * 16))[t & 3] = make_uint4(pk0, pk1, pk2, pk3);
    }
}

// Layer-1 aggregate FUSED with gemm2: 4 lanes/node, x8 gather batches with
// next-batch index prefetch (R20), register accum, then
// h2wd = (relu(agg*dv + b1) @ W2) * dv via LDS W2 + 12-shuffle butterfly.
__global__ __launch_bounds__(256) void aggF_kernel(
        const int* __restrict__ offs, const int* __restrict__ counts,
        const int* __restrict__ csr_src, const float* __restrict__ dinv,
        const unsigned* __restrict__ xwd, const float* __restrict__ b1,
        const float* __restrict__ W2, unsigned* __restrict__ h2wd, int N) {
    __shared__ float ws2[32 * 16];
    for (int i = threadIdx.x; i < 512; i += 256) ws2[i] = W2[i];
    __syncthreads();
    int t = threadIdx.x;
    int q = t & 3;                       // 16B slice
    int node = blockIdx.x * 64 + (t >> 2);
    if (node >= N) return;
    int off = offs[node];
    int deg = counts[node];
    float acc[8];
    {
        uint4 v = ((const uint4*)(xwd + (size_t)node * 16))[q];  // self term
        acc[0] = bflo(v.x); acc[1] = bfhi(v.x);
        acc[2] = bflo(v.y); acc[3] = bfhi(v.y);
        acc[4] = bflo(v.z); acc[5] = bfhi(v.z);
        acc[6] = bflo(v.w); acc[7] = bfhi(v.w);
    }
    int deg8 = deg & ~7;
    int idx[8];
    if (deg8 > 0) {
#pragma unroll
        for (int c = 0; c < 8; ++c) idx[c] = csr_src[off + c];
    }
    int i = 0;
    while (i < deg8) {
        // issue 8 independent gathers with current indices
        uint4 v0 = ((const uint4*)(xwd + (size_t)idx[0] * 16))[q];
        uint4 v1 = ((const uint4*)(xwd + (size_t)idx[1] * 16))[q];
        uint4 v2 = ((const uint4*)(xwd + (size_t)idx[2] * 16))[q];
        uint4 v3 = ((const uint4*)(xwd + (size_t)idx[3] * 16))[q];
        uint4 v4 = ((const uint4*)(xwd + (size_t)idx[4] * 16))[q];
        uint4 v5 = ((const uint4*)(xwd + (size_t)idx[5] * 16))[q];
        uint4 v6 = ((const uint4*)(xwd + (size_t)idx[6] * 16))[q];
        uint4 v7 = ((const uint4*)(xwd + (size_t)idx[7] * 16))[q];
        i += 8;
        if (i < deg8) {                  // prefetch next batch's indices
#pragma unroll
            for (int c = 0; c < 8; ++c) idx[c] = csr_src[off + i + c];
        }
        acc[0] += ((bflo(v0.x) + bflo(v1.x)) + (bflo(v2.x) + bflo(v3.x)))
                + ((bflo(v4.x) + bflo(v5.x)) + (bflo(v6.x) + bflo(v7.x)));
        acc[1] += ((bfhi(v0.x) + bfhi(v1.x)) + (bfhi(v2.x) + bfhi(v3.x)))
                + ((bfhi(v4.x) + bfhi(v5.x)) + (bfhi(v6.x) + bfhi(v7.x)));
        acc[2] += ((bflo(v0.y) + bflo(v1.y)) + (bflo(v2.y) + bflo(v3.y)))
                + ((bflo(v4.y) + bflo(v5.y)) + (bflo(v6.y) + bflo(v7.y)));
        acc[3] += ((bfhi(v0.y) + bfhi(v1.y)) + (bfhi(v2.y) + bfhi(v3.y)))
                + ((bfhi(v4.y) + bfhi(v5.y)) + (bfhi(v6.y) + bfhi(v7.y)));
        acc[4] += ((bflo(v0.z) + bflo(v1.z)) + (bflo(v2.z) + bflo(v3.z)))
                + ((bflo(v4.z) + bflo(v5.z)) + (bflo(v6.z) + bflo(v7.z)));
        acc[5] += ((bfhi(v0.z) + bfhi(v1.z)) + (bfhi(v2.z) + bfhi(v3.z)))
                + ((bfhi(v4.z) + bfhi(v5.z)) + (bfhi(v6.z) + bfhi(v7.z)));
        acc[6] += ((bflo(v0.w) + bflo(v1.w)) + (bflo(v2.w) + bflo(v3.w)))
                + ((bflo(v4.w) + bflo(v5.w)) + (bflo(v6.w) + bflo(v7.w)));
        acc[7] += ((bfhi(v0.w) + bfhi(v1.w)) + (bfhi(v2.w) + bfhi(v3.w)))
                + ((bfhi(v4.w) + bfhi(v5.w)) + (bfhi(v6.w) + bfhi(v7.w)));
    }
    for (; i < deg; ++i) {
        int s = csr_src[off + i];
        uint4 v = ((const uint4*)(xwd + (size_t)s * 16))[q];
        acc[0] += bflo(v.x); acc[1] += bfhi(v.x);
        acc[2] += bflo(v.y); acc[3] += bfhi(v.y);
        acc[4] += bflo(v.z); acc[5] += bfhi(v.z);
        acc[6] += bflo(v.w); acc[7] += bfhi(v.w);
    }
    float dv = dinv[node];
    // fused gemm2: lane q owns k = q*8..q*8+7 of the 32-dim hidden vector
    float part[16];
#pragma unroll
    for (int j = 0; j < 16; ++j) part[j] = 0.0f;
    const float* bq = b1 + q * 8;
#pragma unroll
    for (int k = 0; k < 8; ++k) {
        float h = fmaxf(acc[k] * dv + bq[k], 0.0f);
        const float* wr = ws2 + (q * 8 + k) * 16;
        float4 w0 = *(const float4*)(wr);
        float4 w1 = *(const float4*)(wr + 4);
        float4 w2 = *(const float4*)(wr + 8);
        float4 w3 = *(const float4*)(wr + 12);
        part[0]  += h * w0.x; part[1]  += h * w0.y; part[2]  += h * w0.z; part[3]  += h * w0.w;
        part[4]  += h * w1.x; part[5]  += h * w1.y; part[6]  += h * w1.z; part[7]  += h * w1.w;
        part[8]  += h * w2.x; part[9]  += h * w2.y; part[10] += h * w2.z; part[11] += h * w2.w;
        part[12] += h * w3.x; part[13] += h * w3.y; part[14] += h * w3.z; part[15] += h * w3.w;
    }
    // half-exchange butterfly over the quad: 8 + 4 shfl total.
    float p8[8];
#pragma unroll
    for (int j = 0; j < 8; ++j) {
        float send = (q & 1) ? part[j] : part[j + 8];
        float keep = (q & 1) ? part[j + 8] : part[j];
        p8[j] = keep + __shfl_xor(send, 1, 64);
    }
    float p4[4];
#pragma unroll
    for (int j = 0; j < 4; ++j) {
        float send = (q & 2) ? p8[j] : p8[j + 4];
        float keep = (q & 2) ? p8[j + 4] : p8[j];
        p4[j] = keep + __shfl_xor(send, 2, 64);
    }
    unsigned pk0 = f2bf(p4[0] * dv) | (f2bf(p4[1] * dv) << 16);
    unsigned pk1 = f2bf(p4[2] * dv) | (f2bf(p4[3] * dv) << 16);
    int slot = ((q & 1) << 1) | ((q >> 1) & 1);   // col base /4: q0->0 q1->2 q2->1 q3->3
    ((uint2*)(h2wd + (size_t)node * 8))[slot] = make_uint2(pk0, pk1);
}

// Layer-2 aggregate + fused head, 2 lanes/node, x8 pipelined gather batches.
__global__ __launch_bounds__(256) void aggS16f_kernel(
        const int* __restrict__ offs, const int* __restrict__ counts,
        const int* __restrict__ csr_src, const float* __restrict__ dinv,
        const unsigned* __restrict__ h2wd,
        const float* __restrict__ b2, const float* __restrict__ Wf,
        const float* __restrict__ bf, float* __restrict__ out, int N) {
    __shared__ float bs_[16];
    __shared__ float wf_[16];
    __shared__ float bfv;
    int t = threadIdx.x;
    if (t < 16) { bs_[t] = b2[t]; wf_[t] = Wf[t]; }
    if (t == 0) bfv = bf[0];
    __syncthreads();
    int q = t & 1;                        // 16B slice (8 feats)
    int node = blockIdx.x * 128 + (t >> 1);
    if (node >= N) return;
    int off = offs[node];
    int deg = counts[node];
    float acc[8];
    {
        uint4 v = ((const uint4*)(h2wd + (size_t)node * 8))[q];  // self term
        acc[0] = bflo(v.x); acc[1] = bfhi(v.x);
        acc[2] = bflo(v.y); acc[3] = bfhi(v.y);
        acc[4] = bflo(v.z); acc[5] = bfhi(v.z);
        acc[6] = bflo(v.w); acc[7] = bfhi(v.w);
    }
    int deg8 = deg & ~7;
    int idx[8];
    if (deg8 > 0) {
#pragma unroll
        for (int c = 0; c < 8; ++c) idx[c] = csr_src[off + c];
    }
    int i = 0;
    while (i < deg8) {
        uint4 v0 = ((const uint4*)(h2wd + (size_t)idx[0] * 8))[q];
        uint4 v1 = ((const uint4*)(h2wd + (size_t)idx[1] * 8))[q];
        uint4 v2 = ((const uint4*)(h2wd + (size_t)idx[2] * 8))[q];
        uint4 v3 = ((const uint4*)(h2wd + (size_t)idx[3] * 8))[q];
        uint4 v4 = ((const uint4*)(h2wd + (size_t)idx[4] * 8))[q];
        uint4 v5 = ((const uint4*)(h2wd + (size_t)idx[5] * 8))[q];
        uint4 v6 = ((const uint4*)(h2wd + (size_t)idx[6] * 8))[q];
        uint4 v7 = ((const uint4*)(h2wd + (size_t)idx[7] * 8))[q];
        i += 8;
        if (i < deg8) {
#pragma unroll
            for (int c = 0; c < 8; ++c) idx[c] = csr_src[off + i + c];
        }
        acc[0] += ((bflo(v0.x) + bflo(v1.x)) + (bflo(v2.x) + bflo(v3.x)))
                + ((bflo(v4.x) + bflo(v5.x)) + (bflo(v6.x) + bflo(v7.x)));
        acc[1] += ((bfhi(v0.x) + bfhi(v1.x)) + (bfhi(v2.x) + bfhi(v3.x)))
                + ((bfhi(v4.x) + bfhi(v5.x)) + (bfhi(v6.x) + bfhi(v7.x)));
        acc[2] += ((bflo(v0.y) + bflo(v1.y)) + (bflo(v2.y) + bflo(v3.y)))
                + ((bflo(v4.y) + bflo(v5.y)) + (bflo(v6.y) + bflo(v7.y)));
        acc[3] += ((bfhi(v0.y) + bfhi(v1.y)) + (bfhi(v2.y) + bfhi(v3.y)))
                + ((bfhi(v4.y) + bfhi(v5.y)) + (bfhi(v6.y) + bfhi(v7.y)));
        acc[4] += ((bflo(v0.z) + bflo(v1.z)) + (bflo(v2.z) + bflo(v3.z)))
                + ((bflo(v4.z) + bflo(v5.z)) + (bflo(v6.z) + bflo(v7.z)));
        acc[5] += ((bfhi(v0.z) + bfhi(v1.z)) + (bfhi(v2.z) + bfhi(v3.z)))
                + ((bfhi(v4.z) + bfhi(v5.z)) + (bfhi(v6.z) + bfhi(v7.z)));
        acc[6] += ((bflo(v0.w) + bflo(v1.w)) + (bflo(v2.w) + bflo(v3.w)))
                + ((bflo(v4.w) + bflo(v5.w)) + (bflo(v6.w) + bflo(v7.w)));
        acc[7] += ((bfhi(v0.w) + bfhi(v1.w)) + (bfhi(v2.w) + bfhi(v3.w)))
                + ((bfhi(v4.w) + bfhi(v5.w)) + (bfhi(v6.w) + bfhi(v7.w)));
    }
    for (; i < deg; ++i) {
        int s = csr_src[off + i];
        uint4 v = ((const uint4*)(h2wd + (size_t)s * 8))[q];
        acc[0] += bflo(v.x); acc[1] += bfhi(v.x);
        acc[2] += bflo(v.y); acc[3] += bfhi(v.y);
        acc[4] += bflo(v.z); acc[5] += bfhi(v.z);
        acc[6] += bflo(v.w); acc[7] += bfhi(v.w);
    }
    // fused head: out[node] = relu(acc*dv + b2) . Wf + bf  (pair-split dot)
    float dv = dinv[node];
    const float* bq = bs_ + q * 8;
    const float* wq = wf_ + q * 8;
    float part = 0.f;
#pragma unroll
    for (int k = 0; k < 8; ++k)
        part += fmaxf(acc[k] * dv + bq[k], 0.f) * wq[k];
    part += __shfl_xor(part, 1, 64);  // combine the pair's halves
    if (q == 0) out[node] = part + bfv;
}

extern "C" void kernel_launch(void* const* d_in, const int* in_sizes, int n_in,
                              void* d_out, int out_size, void* d_ws, size_t ws_size,
                              hipStream_t stream) {
    const float* x  = (const float*)d_in[0];
    const int*   ei = (const int*)d_in[1];
    const float* W1 = (const float*)d_in[2];
    const float* b1 = (const float*)d_in[3];
    const float* W2 = (const float*)d_in[4];
    const float* b2 = (const float*)d_in[5];
    const float* Wf = (const float*)d_in[6];
    const float* bf = (const float*)d_in[7];

    int N = in_sizes[0] / 128;
    int E = in_sizes[1] / 2;
    const int* src = ei;       // edge_index[0]
    const int* dst = ei + E;   // edge_index[1]
    int NPB = (N + NBUCK - 1) / NBUCK;  // 196 for N=100k

    // Workspace layout
    size_t Np = ((size_t)N + 3) & ~(size_t)3;
    size_t Ep = ((size_t)E + 3) & ~(size_t)3;
    int* wsI      = (int*)d_ws;
    int* counts   = wsI;                 // Np
    int* offs     = counts + Np;         // Np
    int* bcur     = offs + Np;           // NBUCK
    int* bbase    = bcur + NBUCK;        // NBUCK
    int* csr_src  = bbase + NBUCK;       // Ep
    float* dinv   = (float*)(csr_src + Ep);      // Np
    unsigned* xwd = (unsigned*)(dinv + Np);      // 16*Np u32 (bf16, 64B rows)
    unsigned* staging = xwd + 16 * Np;           // NBUCK*BCAP u32 = 16.8 MB
    // h2wd (8*N u32 = 3.2 MB) aliases staging: staging written by binA2,
    // read last by buildB; h2wd first written by aggF (later). No overlap.
    unsigned* h2wd = staging;
    float* out    = (float*)d_out;

    int nbC  = (E + CHUNK - 1) / CHUNK;  // 782
    int nbG1 = (N + 127) / 128;          // 782 (2 nodes/thread)
    int nbA32 = (N + 63) / 64;   // 64 nodes/block (4 lanes/node)
    int nbA16 = (N + 127) / 128; // 128 nodes/block (2 lanes/node)

    hipMemsetAsync(bcur, 0, NBUCK * sizeof(int), stream);
    binA2_kernel<<<nbC, 512, 0, stream>>>(src, dst, bcur, staging, E, NPB);
    bbase_kernel<<<1, 512, 0, stream>>>(bcur, bbase);
    buildB_kernel<<<NBUCK, 512, 0, stream>>>(bcur, bbase, staging, offs, counts,
                                             dinv, csr_src, N, NPB);
    gemm1_kernel<<<nbG1, 256, 0, stream>>>(x, W1, dinv, xwd, N);
    aggF_kernel<<<nbA32, 256, 0, stream>>>(offs, counts, csr_src, dinv, xwd,
                                           b1, W2, h2wd, N);
    aggS16f_kernel<<<nbA16, 256, 0, stream>>>(offs, counts, csr_src, dinv, h2wd,
                                              b2, Wf, bf, out, N);
}